// Round 15
// baseline (924.768 us; speedup 1.0000x reference)
//
#include <hip/hip_runtime.h>
#include <hip/hip_bf16.h>

#define AS1 __attribute__((address_space(1)))
#define AS3 __attribute__((address_space(3)))

typedef __attribute__((ext_vector_type(8))) short bf16x8;
typedef __attribute__((ext_vector_type(4))) float f32x4;

#define B_ 2
#define S_ 2048
#define D_ 4096
#define H_ 32
#define HD_ 128
#define P_ 30

__device__ __forceinline__ short f2b(float f) {
  union { __hip_bfloat16 h; short s; } u;
  u.h = __float2bfloat16(f);
  return u.s;
}
__device__ __forceinline__ float b2f(short s) {
  union { short s; __hip_bfloat16 h; } u;
  u.s = s;
  return __bfloat162float(u.h);
}
__device__ __forceinline__ void gload16(const void* g, void* l) {
  __builtin_amdgcn_global_load_lds((const AS1 void*)g, (AS3 void*)l, 16, 0, 0);
}

// ---------------- elementwise conversion ----------------
__global__ __launch_bounds__(256) void convert_f32_bf16(const float* __restrict__ in,
                                                        short* __restrict__ out) {
  size_t i = ((size_t)blockIdx.x * 256 + threadIdx.x) * 4;
  float4 v = *reinterpret_cast<const float4*>(in + i);
  short4 o;
  o.x = f2b(v.x); o.y = f2b(v.y); o.z = f2b(v.z); o.w = f2b(v.w);
  *reinterpret_cast<short4*>(out + i) = o;
}

// prefix (30 x 4096 f32) -> padded 128 x 4096 bf16 (zeros beyond row 29)
__global__ __launch_bounds__(256) void pad_prefix(const float* __restrict__ p,
                                                  short* __restrict__ pb) {
  int i = blockIdx.x * 256 + threadIdx.x;
  int row = i >> 12, col = i & 4095;
  pb[i] = (row < P_) ? f2b(p[row * D_ + col]) : (short)0;
}

// W (K x N) f32 -> Wt (N x K) bf16, 32x32 LDS tiles
__global__ void transpose_convert(const float* __restrict__ W, short* __restrict__ Wt,
                                  int K, int N) {
  __shared__ float t[32][33];
  int bx = blockIdx.x, by = blockIdx.y;
  int tx = threadIdx.x, ty = threadIdx.y;
#pragma unroll
  for (int i = 0; i < 4; ++i) {
    int r = ty * 4 + i;
    t[r][tx] = W[(size_t)(by * 32 + r) * N + bx * 32 + tx];
  }
  __syncthreads();
#pragma unroll
  for (int i = 0; i < 4; ++i) {
    int r = ty * 4 + i;
    Wt[(size_t)(bx * 32 + r) * K + by * 32 + tx] = f2b(t[tx][r]);
  }
}

// in-place RoPE on (B,S,H,HD) bf16; blockIdx.y selects q/k buffer.
// q is pre-scaled by 1/sqrt(HD) (folded attention scale).
__global__ __launch_bounds__(256) void rope_kernel(short* __restrict__ q,
                                                   short* __restrict__ k,
                                                   const float* __restrict__ fc,
                                                   const float* __restrict__ fs) {
  short* t = blockIdx.y ? k : q;
  const float qs = blockIdx.y ? 1.0f : 0.08838834764831845f;
  size_t g = ((size_t)blockIdx.x * 256 + threadIdx.x) * 8;
  int d = (int)(g & 127);
  int s = (int)((g >> 12) & 2047);
  bf16x8 v = *reinterpret_cast<bf16x8*>(t + g);
  int i0 = d >> 1;
  float4 c = *reinterpret_cast<const float4*>(fc + (size_t)s * 64 + i0);
  float4 sn = *reinterpret_cast<const float4*>(fs + (size_t)s * 64 + i0);
  float cc[4] = {c.x, c.y, c.z, c.w};
  float ss[4] = {sn.x, sn.y, sn.z, sn.w};
  bf16x8 o;
#pragma unroll
  for (int p = 0; p < 4; ++p) {
    float t0 = b2f(v[2 * p]), t1 = b2f(v[2 * p + 1]);
    o[2 * p] = f2b((t0 * cc[p] - t1 * ss[p]) * qs);
    o[2 * p + 1] = f2b((t0 * ss[p] + t1 * cc[p]) * qs);
  }
  *reinterpret_cast<bf16x8*>(t + g) = o;
}

// ---------------- small GEMM (m97 structure) for prefix projections ----------------
// OM: 1 = bf16 out (MxN), 3 = bf16 transposed out (C^T, N x M layout)
template <int OM>
__global__ __launch_bounds__(256) void gemm_bt(const short* __restrict__ A,
                                               const short* __restrict__ Bt,
                                               void* __restrict__ Cv,
                                               int M, int N, int K) {
  __shared__ short As[128 * 32];
  __shared__ short Bs[128 * 32];
  const int tid = threadIdx.x;
  const int lane = tid & 63;
  const int wbase = tid & 192;
  const int wr = ((tid >> 7) & 1) * 64;
  const int wc = ((tid >> 6) & 1) * 64;
  const int lr = lane & 15;
  const int lk = (lane >> 4) * 8;
  int lin = blockIdx.y * gridDim.x + blockIdx.x;
  int nwg = gridDim.x * gridDim.y;
  int cpx = nwg >> 3;
  int swz = (lin & 7) * cpx + (lin >> 3);
  const int bm = swz / gridDim.x, bn = swz % gridDim.x;
  f32x4 acc[4][4] = {};
  const short* Ab = A + (size_t)bm * 128 * K;
  const short* Bb = Bt + (size_t)bn * 128 * K;
  for (int kt = 0; kt < K; kt += 32) {
    __syncthreads();
#pragma unroll
    for (int i = 0; i < 2; ++i) {
      int f = i * 256 + tid;
      int row = f >> 2, col = (f & 3) * 8;
      gload16(Ab + (size_t)row * K + kt + col, &As[(i * 256 + wbase) * 8]);
      gload16(Bb + (size_t)row * K + kt + col, &Bs[(i * 256 + wbase) * 8]);
    }
    __syncthreads();
    bf16x8 af[4], bfr[4];
#pragma unroll
    for (int m = 0; m < 4; ++m)
      af[m] = *reinterpret_cast<const bf16x8*>(&As[(wr + m * 16 + lr) * 32 + lk]);
#pragma unroll
    for (int n = 0; n < 4; ++n)
      bfr[n] = *reinterpret_cast<const bf16x8*>(&Bs[(wc + n * 16 + lr) * 32 + lk]);
#pragma unroll
    for (int m = 0; m < 4; ++m)
#pragma unroll
      for (int n = 0; n < 4; ++n)
        acc[m][n] = __builtin_amdgcn_mfma_f32_16x16x32_bf16(af[m], bfr[n], acc[m][n], 0, 0, 0);
  }
  const int row0 = bm * 128 + wr + (lane >> 4) * 4;
  const int col0 = bn * 128 + wc + lr;
  if constexpr (OM == 3) {
    short* C = (short*)Cv;
#pragma unroll
    for (int m = 0; m < 4; ++m)
#pragma unroll
      for (int n = 0; n < 4; ++n) {
        short4 pk;
        pk.x = f2b(acc[m][n][0]); pk.y = f2b(acc[m][n][1]);
        pk.z = f2b(acc[m][n][2]); pk.w = f2b(acc[m][n][3]);
        size_t idx = (size_t)(col0 + n * 16) * M + row0 + m * 16;
        *reinterpret_cast<short4*>(&C[idx]) = pk;
      }
  } else {
#pragma unroll
    for (int m = 0; m < 4; ++m)
#pragma unroll
      for (int n = 0; n < 4; ++n)
#pragma unroll
        for (int j = 0; j < 4; ++j) {
          size_t idx = (size_t)(row0 + m * 16 + j) * N + col0 + n * 16;
          ((short*)Cv)[idx] = f2b(acc[m][n][j]);
        }
  }
}

// ---------------- 256x256 8-wave GEMM, barrier-free inner tile ----------------
// All of tile t+1 (4 B octets + 4 A octets per wave) staged into slot ns at the
// START of tile t -> no LDS write ever touches the slot being read -> zero
// intra-tile barriers. Waves free-run; LDS reads of one wave overlap MFMA of
// others. One vmcnt(0)+barrier per tile (slot handoff). B-frags reused across
// the mh pair (24 ds_read_b128/tile/wave).
#define MFMA16(mh)                                                              \
  _Pragma("unroll") for (int mm = 0; mm < 4; ++mm)                              \
    _Pragma("unroll") for (int nn = 0; nn < 4; ++nn)                            \
      acc[(mh)*4 + mm][nn] = __builtin_amdgcn_mfma_f32_16x16x32_bf16(           \
          af[mm], bf[nn], acc[(mh)*4 + mm][nn], 0, 0, 0);

template <int OM>
__global__ __launch_bounds__(512, 2) void gemm256(const short* __restrict__ A,
                                                  const short* __restrict__ Bt,
                                                  void* __restrict__ Cv,
                                                  int M, int N, int K) {
  __shared__ short As[2][256 * 64];
  __shared__ short Bs[2][256 * 64];
  const int tid = threadIdx.x;
  const int w = tid >> 6;
  const int lane = tid & 63;
  const int lr = lane & 15, lg = lane >> 4;
  const int wr = (w >> 2) * 128;
  const int wc = (w & 3) * 64;
  int lin = blockIdx.y * gridDim.x + blockIdx.x;
  int nwg = gridDim.x * gridDim.y;
  int cpx = nwg >> 3;
  int swz = (lin & 7) * cpx + (lin >> 3);
  const int bm = swz / gridDim.x, bn = swz % gridDim.x;

  const short* Ab = A + (size_t)bm * 256 * K;
  const short* Bb = Bt + (size_t)bn * 256 * K;
  const int NT = K >> 6;

  f32x4 acc[8][4] = {};

  auto stA = [&](int slot_, int r0, int kt) {
    int row = r0 + (lane >> 3);
    int gsrc = (lane & 7) ^ ((lane >> 3) & 7);
    gload16(Ab + (size_t)row * K + kt + gsrc * 8, &As[slot_][r0 * 64]);
  };
  auto stB = [&](int slot_, int r0, int kt) {
    int row = r0 + (lane >> 3);
    int gsrc = (lane & 7) ^ ((lane >> 3) & 7);
    gload16(Bb + (size_t)row * K + kt + gsrc * 8, &Bs[slot_][r0 * 64]);
  };

  const int q2 = w * 2, q4 = w * 4;
  const int rt0 = (q2 < 8 ? 0 : 64) + q2 * 8;
  const int rt1 = (q2 + 1 < 8 ? 0 : 64) + (q2 + 1) * 8;

  // stage one full tile (per wave: 4 B octets + 4 A octets)
  auto stageTile = [&](int slot_, int kt) {
#pragma unroll
    for (int i = 0; i < 4; ++i) stB(slot_, (q4 + i) * 8, kt);
    stA(slot_, rt0, kt); stA(slot_, 64 + rt0, kt);
    stA(slot_, rt1, kt); stA(slot_, 64 + rt1, kt);
  };

  // prologue: tile 0 into slot 0
  stageTile(0, 0);
  asm volatile("s_waitcnt vmcnt(0)" ::: "memory");
  __builtin_amdgcn_s_barrier();

  for (int t = 0; t < NT; ++t) {
    const int slot = t & 1;
    const int ns = slot ^ 1;
    if (t + 1 < NT) stageTile(ns, (t + 1) << 6);

#pragma unroll
    for (int kh = 0; kh < 2; ++kh) {
      const int pg = ((kh * 4 + lg) ^ (lr & 7)) * 8;
      bf16x8 bf[4], af[4];
#pragma unroll
      for (int nn = 0; nn < 4; ++nn)
        bf[nn] = *(const bf16x8*)&Bs[slot][(wc + nn * 16 + lr) * 64 + pg];
#pragma unroll
      for (int mm = 0; mm < 4; ++mm)
        af[mm] = *(const bf16x8*)&As[slot][(wr + mm * 16 + lr) * 64 + pg];
      __builtin_amdgcn_s_setprio(1);
      MFMA16(0)
      __builtin_amdgcn_s_setprio(0);
#pragma unroll
      for (int mm = 0; mm < 4; ++mm)
        af[mm] = *(const bf16x8*)&As[slot][(wr + 64 + mm * 16 + lr) * 64 + pg];
      __builtin_amdgcn_s_setprio(1);
      MFMA16(1)
      __builtin_amdgcn_s_setprio(0);
    }

    asm volatile("s_waitcnt vmcnt(0)" ::: "memory");
    __builtin_amdgcn_s_barrier();
  }

  const int row0 = bm * 256 + wr + lg * 4;
  const int col0 = bn * 256 + wc + lr;
  if constexpr (OM == 2) {
    short* C = (short*)Cv;
#pragma unroll
    for (int mf = 0; mf < 8; ++mf)
#pragma unroll
      for (int n = 0; n < 4; ++n) {
        int r0 = row0 + mf * 16;
        int bb = r0 >> 11, s0 = r0 & 2047;
        short4 pk;
        pk.x = f2b(acc[mf][n][0]); pk.y = f2b(acc[mf][n][1]);
        pk.z = f2b(acc[mf][n][2]); pk.w = f2b(acc[mf][n][3]);
        size_t idx = ((size_t)(bb * 4096 + col0 + n * 16)) * 2048 + s0;
        *reinterpret_cast<short4*>(&C[idx]) = pk;
      }
  } else {
#pragma unroll
    for (int mf = 0; mf < 8; ++mf)
#pragma unroll
      for (int n = 0; n < 4; ++n)
#pragma unroll
        for (int j = 0; j < 4; ++j) {
          size_t idx = (size_t)(row0 + mf * 16 + j) * N + col0 + n * 16;
          if constexpr (OM == 1) ((short*)Cv)[idx] = f2b(acc[mf][n][j]);
          else ((float*)Cv)[idx] = acc[mf][n][j];
        }
  }
}

// ---------------- fused flash attention + gated prefix, 256 q-rows/block ----------------
// 16 waves x 16 rows, LPT grid. K AND V double-buffered via global_load_lds:
// ONE barrier per tile. Q pre-scaled (rope). Masking only on diag tiles. T13 defer-max.
// LDS: Ks 32K + Vs 32K + Ps 32K = 96 KB.
__global__ __launch_bounds__(1024, 4) void attn_kernel(
    const short* __restrict__ qb, const short* __restrict__ kb, const short* __restrict__ vt,
    const short* __restrict__ pkb, const short* __restrict__ pvt,
    const float* __restrict__ gate, short* __restrict__ ab) {
  __shared__ short Ks[2][64 * 128];
  __shared__ short Vs[2][128 * 64];
  __shared__ short Ps[16][16 * 64];
  const int tid = threadIdx.x;
  const int wave = tid >> 6, lane = tid & 63;
  const int lr = lane & 15, lg = lane >> 4;
  const int lin = blockIdx.x;
  const int qt = 7 - (lin >> 6);     // heavy blocks dispatch first (LPT)
  const int bh = lin & 63;
  const int b = bh >> 5, h = bh & 31;

  bf16x8 aq[4];
  {
    const short* qrow = qb + ((size_t)(b * S_ + qt * 256 + wave * 16 + lr) * H_ + h) * HD_;
#pragma unroll
    for (int kk = 0; kk < 4; ++kk)
      aq[kk] = *reinterpret_cast<const bf16x8*>(qrow + kk * 32 + lg * 8);
  }

  float m = -1e30f, l = 0.f, l2 = 0.f;
  f32x4 o[8] = {}, o2[8] = {};

  const short* kb_bh = kb + ((size_t)b * S_ * H_ + h) * HD_;
  const short* vt_bh = vt + ((size_t)(b * H_ + h)) * HD_ * S_;

  auto stageK = [&](int t, int buf) {
    int row = tid >> 4;
    int col = ((tid & 15) ^ (row & 7)) * 8;
    gload16(kb_bh + (size_t)(t * 64 + row) * (H_ * HD_) + col,
            &Ks[buf][(tid & 960) * 8]);
  };
  auto stagePK = [&](int buf) {
    int row = tid >> 4;
    int col = ((tid & 15) ^ (row & 7)) * 8;
    gload16(pkb + (size_t)row * 4096 + h * HD_ + col, &Ks[buf][(tid & 960) * 8]);
  };
  auto stageV = [&](int t, int buf) {
    int row = tid >> 3;
    int col = ((tid & 7) ^ (row & 7)) * 8;
    gload16(vt_bh + (size_t)row * S_ + t * 64 + col, &Vs[buf][(tid & 1016) * 8]);
  };
  auto stagePV = [&](int buf) {
    int row = tid >> 3;
    int col = ((tid & 7) ^ (row & 7)) * 8;
    gload16(pvt + ((size_t)h * HD_ + row) * 128 + col, &Vs[buf][(tid & 1016) * 8]);
  };

  auto qkt = [&](int buf, f32x4 sc[4]) {
    __builtin_amdgcn_s_setprio(1);
#pragma unroll
    for (int cb = 0; cb < 4; ++cb) {
      int tok = cb * 16 + lr;
#pragma unroll
      for (int kk = 0; kk < 4; ++kk) {
        int addr = tok * 128 + (((kk * 4 + lg) ^ (tok & 7)) * 8);
        bf16x8 bk = *reinterpret_cast<const bf16x8*>(&Ks[buf][addr]);
        sc[cb] = __builtin_amdgcn_mfma_f32_16x16x32_bf16(bk, aq[kk], sc[cb], 0, 0, 0);
      }
    }
    __builtin_amdgcn_s_setprio(0);
  };
  auto pv = [&](int buf, f32x4* acc_) {
#pragma unroll
    for (int kk = 0; kk < 2; ++kk) {
      bf16x8 ap = *reinterpret_cast<const bf16x8*>(
          &Ps[wave][lr * 64 + (((kk * 4 + lg) ^ (lr & 7)) * 8)]);
      __builtin_amdgcn_s_setprio(1);
#pragma unroll
      for (int nb = 0; nb < 8; ++nb) {
        int d = nb * 16 + lr;
        bf16x8 bv = *reinterpret_cast<const bf16x8*>(
            &Vs[buf][d * 64 + (((kk * 4 + lg) ^ (lr & 7)) * 8)]);
        acc_[nb] = __builtin_amdgcn_mfma_f32_16x16x32_bf16(ap, bv, acc_[nb], 0, 0, 0);
      }
      __builtin_amdgcn_s_setprio(0);
    }
  };

  auto process = [&](int t, bool diag) {
    const int buf = t & 1;
    f32x4 sc[4] = {};
    qkt(buf, sc);
    if (diag) {
      const int rowg = qt * 256 + wave * 16 + lr;
#pragma unroll
      for (int cb = 0; cb < 4; ++cb)
#pragma unroll
        for (int j = 0; j < 4; ++j) {
          int colg = t * 64 + cb * 16 + lg * 4 + j;
          if (colg > rowg) sc[cb][j] = -1e30f;
        }
    }
    float mx = sc[0][0];
#pragma unroll
    for (int cb = 0; cb < 4; ++cb)
#pragma unroll
      for (int j = 0; j < 4; ++j) mx = fmaxf(mx, sc[cb][j]);
    mx = fmaxf(mx, __shfl_xor(mx, 16));
    mx = fmaxf(mx, __shfl_xor(mx, 32));
    if (!__all(mx <= m + 8.f)) {
      float mn = fmaxf(m, mx);
      float alpha = __expf(m - mn);
      m = mn;
      l *= alpha;
      f32x4 av;
#pragma unroll
      for (int j = 0; j < 4; ++j) av[j] = __shfl(alpha, lg * 4 + j);
#pragma unroll
      for (int nb = 0; nb < 8; ++nb)
#pragma unroll
        for (int j = 0; j < 4; ++j) o[nb][j] *= av[j];
    }
    float rs = 0.f;
#pragma unroll
    for (int cb = 0; cb < 4; ++cb) {
      short4 pk;
      float p0 = __expf(sc[cb][0] - m);
      float p1 = __expf(sc[cb][1] - m);
      float p2 = __expf(sc[cb][2] - m);
      float p3 = __expf(sc[cb][3] - m);
      rs += (p0 + p1) + (p2 + p3);
      pk.x = f2b(p0); pk.y = f2b(p1); pk.z = f2b(p2); pk.w = f2b(p3);
      int gran = (cb * 2 + (lg >> 1)) ^ (lr & 7);
      *reinterpret_cast<short4*>(&Ps[wave][lr * 64 + gran * 8 + (lg & 1) * 4]) = pk;
    }
    rs += __shfl_xor(rs, 16);
    rs += __shfl_xor(rs, 32);
    l += rs;
    pv(buf, o);
  };

  auto processPrefix = [&]() {
    f32x4 sc[4] = {};
    qkt(0, sc);
#pragma unroll
    for (int cb = 0; cb < 4; ++cb)
#pragma unroll
      for (int j = 0; j < 4; ++j) {
        int coll = cb * 16 + lg * 4 + j;
        if (coll >= P_) sc[cb][j] = -1e30f;
      }
    float mx = sc[0][0];
#pragma unroll
    for (int cb = 0; cb < 4; ++cb)
#pragma unroll
      for (int j = 0; j < 4; ++j) mx = fmaxf(mx, sc[cb][j]);
    mx = fmaxf(mx, __shfl_xor(mx, 16));
    mx = fmaxf(mx, __shfl_xor(mx, 32));
    float rs = 0.f;
#pragma unroll
    for (int cb = 0; cb < 4; ++cb) {
      short4 pk;
      float p0 = __expf(sc[cb][0] - mx);
      float p1 = __expf(sc[cb][1] - mx);
      float p2 = __expf(sc[cb][2] - mx);
      float p3 = __expf(sc[cb][3] - mx);
      rs += (p0 + p1) + (p2 + p3);
      pk.x = f2b(p0); pk.y = f2b(p1); pk.z = f2b(p2); pk.w = f2b(p3);
      int gran = (cb * 2 + (lg >> 1)) ^ (lr & 7);
      *reinterpret_cast<short4*>(&Ps[wave][lr * 64 + gran * 8 + (lg & 1) * 4]) = pk;
    }
    rs += __shfl_xor(rs, 16);
    rs += __shfl_xor(rs, 32);
    l2 = rs;
    pv(0, o2);
  };

  const int nt = 4 * (qt + 1);

  stagePK(0);
  stagePV(0);
  __syncthreads();
  processPrefix();
  __syncthreads();

  stageK(0, 0);
  stageV(0, 0);
  __syncthreads();
  for (int t = 0; t < nt; ++t) {
    if (t + 1 < nt) {
      stageK(t + 1, (t + 1) & 1);
      stageV(t + 1, (t + 1) & 1);
    }
    process(t, t >= 4 * qt);
    __syncthreads();
  }

  {
    float g = tanhf(gate[h]);
    f32x4 lv, lv2;
#pragma unroll
    for (int j = 0; j < 4; ++j) {
      lv[j] = __shfl(l, lg * 4 + j);
      lv2[j] = __shfl(l2, lg * 4 + j);
    }
#pragma unroll
    for (int j = 0; j < 4; ++j) {
      int q = qt * 256 + wave * 16 + lg * 4 + j;
      float inv = 1.f / lv[j];
      float inv2 = g / lv2[j];
      size_t base = ((size_t)(b * S_ + q) * H_ + h) * HD_;
#pragma unroll
      for (int nb = 0; nb < 8; ++nb)
        ab[base + nb * 16 + lr] = f2b(o[nb][j] * inv + o2[nb][j] * inv2);
    }
  }
}

// ---------------- launcher ----------------
extern "C" void kernel_launch(void* const* d_in, const int* in_sizes, int n_in,
                              void* d_out, int out_size, void* d_ws, size_t ws_size,
                              hipStream_t stream) {
  const float* x = (const float*)d_in[0];
  const float* fc = (const float*)d_in[1];
  const float* fs = (const float*)d_in[2];
  const float* prefix = (const float*)d_in[3];
  const float* gate = (const float*)d_in[4];
  const float* wq = (const float*)d_in[5];
  const float* wk = (const float*)d_in[6];
  const float* wv = (const float*)d_in[7];
  const float* wo = (const float*)d_in[8];
  float* out = (float*)d_out;

  char* ws = (char*)d_ws;
  const size_t SZ = (size_t)4096 * 4096 * 2;
  short* xb = (short*)(ws);
  short* wT = (short*)(ws + SZ);
  short* qbuf = (short*)(ws + 2 * SZ);
  short* kbuf = (short*)(ws + 3 * SZ);
  short* vT = (short*)(ws + 4 * SZ);
  short* pb = (short*)(ws + 5 * SZ);
  short* pkb = (short*)(ws + 5 * SZ + (1 << 20));
  short* pvt = (short*)(ws + 5 * SZ + (2 << 20));
  short* abuf = xb;  // alias: x_bf16 dead after V projection

  dim3 tcg(128, 128), tcb(32, 8);
  dim3 gg(16, 16), gp(32, 1);

  convert_f32_bf16<<<16384, 256, 0, stream>>>(x, xb);
  pad_prefix<<<2048, 256, 0, stream>>>(prefix, pb);

  transpose_convert<<<tcg, tcb, 0, stream>>>(wq, wT, 4096, 4096);
  gemm256<1><<<gg, 512, 0, stream>>>(xb, wT, qbuf, 4096, 4096, 4096);

  transpose_convert<<<tcg, tcb, 0, stream>>>(wk, wT, 4096, 4096);
  gemm256<1><<<gg, 512, 0, stream>>>(xb, wT, kbuf, 4096, 4096, 4096);
  gemm_bt<1><<<gp, 256, 0, stream>>>(pb, wT, pkb, 128, 4096, 4096);

  transpose_convert<<<tcg, tcb, 0, stream>>>(wv, wT, 4096, 4096);
  gemm256<2><<<gg, 512, 0, stream>>>(xb, wT, vT, 4096, 4096, 4096);
  gemm_bt<3><<<gp, 256, 0, stream>>>(pb, wT, pvt, 128, 4096, 4096);

  rope_kernel<<<dim3(8192, 2), 256, 0, stream>>>(qbuf, kbuf, fc, fs);

  attn_kernel<<<512, 1024, 0, stream>>>(qbuf, kbuf, vT, pkb, pvt, gate, abuf);

  transpose_convert<<<tcg, tcb, 0, stream>>>(wo, wT, 4096, 4096);
  gemm256<0><<<gg, 512, 0, stream>>>(abuf, wT, out, 4096, 4096, 4096);
}

// Round 16
// 917.580 us; speedup vs baseline: 1.0078x; 1.0078x over previous
//
#include <hip/hip_runtime.h>
#include <hip/hip_bf16.h>

#define AS1 __attribute__((address_space(1)))
#define AS3 __attribute__((address_space(3)))

typedef __attribute__((ext_vector_type(8))) short bf16x8;
typedef __attribute__((ext_vector_type(4))) float f32x4;
typedef __attribute__((ext_vector_type(16))) float f32x16;

#define B_ 2
#define S_ 2048
#define D_ 4096
#define H_ 32
#define HD_ 128
#define P_ 30

__device__ __forceinline__ short f2b(float f) {
  union { __hip_bfloat16 h; short s; } u;
  u.h = __float2bfloat16(f);
  return u.s;
}
__device__ __forceinline__ float b2f(short s) {
  union { short s; __hip_bfloat16 h; } u;
  u.s = s;
  return __bfloat162float(u.h);
}
__device__ __forceinline__ void gload16(const void* g, void* l) {
  __builtin_amdgcn_global_load_lds((const AS1 void*)g, (AS3 void*)l, 16, 0, 0);
}

// ---------------- elementwise conversion ----------------
__global__ __launch_bounds__(256) void convert_f32_bf16(const float* __restrict__ in,
                                                        short* __restrict__ out) {
  size_t i = ((size_t)blockIdx.x * 256 + threadIdx.x) * 4;
  float4 v = *reinterpret_cast<const float4*>(in + i);
  short4 o;
  o.x = f2b(v.x); o.y = f2b(v.y); o.z = f2b(v.z); o.w = f2b(v.w);
  *reinterpret_cast<short4*>(out + i) = o;
}

// prefix (30 x 4096 f32) -> padded 128 x 4096 bf16 (zeros beyond row 29)
__global__ __launch_bounds__(256) void pad_prefix(const float* __restrict__ p,
                                                  short* __restrict__ pb) {
  int i = blockIdx.x * 256 + threadIdx.x;
  int row = i >> 12, col = i & 4095;
  pb[i] = (row < P_) ? f2b(p[row * D_ + col]) : (short)0;
}

// W (K x N) f32 -> Wt (N x K) bf16, 32x32 LDS tiles
__global__ void transpose_convert(const float* __restrict__ W, short* __restrict__ Wt,
                                  int K, int N) {
  __shared__ float t[32][33];
  int bx = blockIdx.x, by = blockIdx.y;
  int tx = threadIdx.x, ty = threadIdx.y;
#pragma unroll
  for (int i = 0; i < 4; ++i) {
    int r = ty * 4 + i;
    t[r][tx] = W[(size_t)(by * 32 + r) * N + bx * 32 + tx];
  }
  __syncthreads();
#pragma unroll
  for (int i = 0; i < 4; ++i) {
    int r = ty * 4 + i;
    Wt[(size_t)(bx * 32 + r) * K + by * 32 + tx] = f2b(t[tx][r]);
  }
}

// in-place RoPE on (B,S,H,HD) bf16; blockIdx.y selects q/k buffer.
// q is pre-scaled by 1/sqrt(HD) (folded attention scale).
__global__ __launch_bounds__(256) void rope_kernel(short* __restrict__ q,
                                                   short* __restrict__ k,
                                                   const float* __restrict__ fc,
                                                   const float* __restrict__ fs) {
  short* t = blockIdx.y ? k : q;
  const float qs = blockIdx.y ? 1.0f : 0.08838834764831845f;
  size_t g = ((size_t)blockIdx.x * 256 + threadIdx.x) * 8;
  int d = (int)(g & 127);
  int s = (int)((g >> 12) & 2047);
  bf16x8 v = *reinterpret_cast<bf16x8*>(t + g);
  int i0 = d >> 1;
  float4 c = *reinterpret_cast<const float4*>(fc + (size_t)s * 64 + i0);
  float4 sn = *reinterpret_cast<const float4*>(fs + (size_t)s * 64 + i0);
  float cc[4] = {c.x, c.y, c.z, c.w};
  float ss[4] = {sn.x, sn.y, sn.z, sn.w};
  bf16x8 o;
#pragma unroll
  for (int p = 0; p < 4; ++p) {
    float t0 = b2f(v[2 * p]), t1 = b2f(v[2 * p + 1]);
    o[2 * p] = f2b((t0 * cc[p] - t1 * ss[p]) * qs);
    o[2 * p + 1] = f2b((t0 * ss[p] + t1 * cc[p]) * qs);
  }
  *reinterpret_cast<bf16x8*>(t + g) = o;
}

// ---------------- small GEMM (m97 structure) for prefix projections ----------------
// OM: 1 = bf16 out (MxN), 3 = bf16 transposed out (C^T, N x M layout)
template <int OM>
__global__ __launch_bounds__(256) void gemm_bt(const short* __restrict__ A,
                                               const short* __restrict__ Bt,
                                               void* __restrict__ Cv,
                                               int M, int N, int K) {
  __shared__ short As[128 * 32];
  __shared__ short Bs[128 * 32];
  const int tid = threadIdx.x;
  const int lane = tid & 63;
  const int wbase = tid & 192;
  const int wr = ((tid >> 7) & 1) * 64;
  const int wc = ((tid >> 6) & 1) * 64;
  const int lr = lane & 15;
  const int lk = (lane >> 4) * 8;
  int lin = blockIdx.y * gridDim.x + blockIdx.x;
  int nwg = gridDim.x * gridDim.y;
  int cpx = nwg >> 3;
  int swz = (lin & 7) * cpx + (lin >> 3);
  const int bm = swz / gridDim.x, bn = swz % gridDim.x;
  f32x4 acc[4][4] = {};
  const short* Ab = A + (size_t)bm * 128 * K;
  const short* Bb = Bt + (size_t)bn * 128 * K;
  for (int kt = 0; kt < K; kt += 32) {
    __syncthreads();
#pragma unroll
    for (int i = 0; i < 2; ++i) {
      int f = i * 256 + tid;
      int row = f >> 2, col = (f & 3) * 8;
      gload16(Ab + (size_t)row * K + kt + col, &As[(i * 256 + wbase) * 8]);
      gload16(Bb + (size_t)row * K + kt + col, &Bs[(i * 256 + wbase) * 8]);
    }
    __syncthreads();
    bf16x8 af[4], bfr[4];
#pragma unroll
    for (int m = 0; m < 4; ++m)
      af[m] = *reinterpret_cast<const bf16x8*>(&As[(wr + m * 16 + lr) * 32 + lk]);
#pragma unroll
    for (int n = 0; n < 4; ++n)
      bfr[n] = *reinterpret_cast<const bf16x8*>(&Bs[(wc + n * 16 + lr) * 32 + lk]);
#pragma unroll
    for (int m = 0; m < 4; ++m)
#pragma unroll
      for (int n = 0; n < 4; ++n)
        acc[m][n] = __builtin_amdgcn_mfma_f32_16x16x32_bf16(af[m], bfr[n], acc[m][n], 0, 0, 0);
  }
  const int row0 = bm * 128 + wr + (lane >> 4) * 4;
  const int col0 = bn * 128 + wc + lr;
  if constexpr (OM == 3) {
    short* C = (short*)Cv;
#pragma unroll
    for (int m = 0; m < 4; ++m)
#pragma unroll
      for (int n = 0; n < 4; ++n) {
        short4 pk;
        pk.x = f2b(acc[m][n][0]); pk.y = f2b(acc[m][n][1]);
        pk.z = f2b(acc[m][n][2]); pk.w = f2b(acc[m][n][3]);
        size_t idx = (size_t)(col0 + n * 16) * M + row0 + m * 16;
        *reinterpret_cast<short4*>(&C[idx]) = pk;
      }
  } else {
#pragma unroll
    for (int m = 0; m < 4; ++m)
#pragma unroll
      for (int n = 0; n < 4; ++n)
#pragma unroll
        for (int j = 0; j < 4; ++j) {
          size_t idx = (size_t)(row0 + m * 16 + j) * N + col0 + n * 16;
          ((short*)Cv)[idx] = f2b(acc[m][n][j]);
        }
  }
}

// ---------------- 256x256 8-wave GEMM, v14 phase skeleton + 32x32x16 MFMA ----------------
// 4 phases per K=64 tile, one kstep (k16) each: 6 ds_read_b128 + 8 mfma_32x32x16.
// Staging (v14-verified): P1 = B01(t+1)+A-bottom(t+1), P2 = B23(t+1),
// P4 = A-top(t+2) into current slot; vmcnt(2) at tile end.
// C/D layout (m74/m101): col = lane&31, row = (reg&3) + 8*(reg>>2) + 4*(lane>>5).
#define PH_SYNC_PRE                                                             \
  __builtin_amdgcn_s_barrier();                                                 \
  asm volatile("s_waitcnt lgkmcnt(0)" ::: "memory");                            \
  __builtin_amdgcn_sched_barrier(0);                                            \
  __builtin_amdgcn_s_setprio(1);

#define PH_SYNC_POST                                                            \
  __builtin_amdgcn_s_setprio(0);                                                \
  __builtin_amdgcn_s_barrier();

#define PHASE32(ks, STAGE, TAIL)                                                \
  {                                                                             \
    bf16x8 af[4], bfv[2];                                                       \
    const int gsel = (ks) * 2 + kg;                                             \
    _Pragma("unroll") for (int mb = 0; mb < 4; ++mb) {                          \
      int row = wr + mb * 32 + l31;                                             \
      af[mb] = *(const bf16x8*)&As[slot][row * 64 + ((gsel ^ (row & 7)) * 8)];  \
    }                                                                           \
    _Pragma("unroll") for (int nb = 0; nb < 2; ++nb) {                          \
      int brow = wc + nb * 32 + l31;                                            \
      bfv[nb] = *(const bf16x8*)&Bs[slot][brow * 64 + ((gsel ^ (brow & 7)) * 8)];\
    }                                                                           \
    STAGE;                                                                      \
    PH_SYNC_PRE                                                                 \
    _Pragma("unroll") for (int mb = 0; mb < 4; ++mb)                            \
      _Pragma("unroll") for (int nb = 0; nb < 2; ++nb)                          \
        acc[mb][nb] = __builtin_amdgcn_mfma_f32_32x32x16_bf16(                  \
            af[mb], bfv[nb], acc[mb][nb], 0, 0, 0);                             \
    __builtin_amdgcn_s_setprio(0);                                              \
    TAIL;                                                                       \
    __builtin_amdgcn_s_barrier();                                               \
  }

template <int OM>
__global__ __launch_bounds__(512, 2) void gemm256(const short* __restrict__ A,
                                                  const short* __restrict__ Bt,
                                                  void* __restrict__ Cv,
                                                  int M, int N, int K) {
  __shared__ short As[2][256 * 64];
  __shared__ short Bs[2][256 * 64];
  const int tid = threadIdx.x;
  const int w = tid >> 6;
  const int lane = tid & 63;
  const int l31 = lane & 31;
  const int kg = lane >> 5;        // k-group 0/1 within kstep
  const int wr = (w >> 2) * 128;
  const int wc = (w & 3) * 64;
  int lin = blockIdx.y * gridDim.x + blockIdx.x;
  int nwg = gridDim.x * gridDim.y;
  int cpx = nwg >> 3;
  int swz = (lin & 7) * cpx + (lin >> 3);
  const int bm = swz / gridDim.x, bn = swz % gridDim.x;

  const short* Ab = A + (size_t)bm * 256 * K;
  const short* Bb = Bt + (size_t)bn * 256 * K;
  const int NT = K >> 6;

  f32x16 acc[4][2] = {};

  auto stA = [&](int slot_, int r0, int kt) {
    int row = r0 + (lane >> 3);
    int gsrc = (lane & 7) ^ ((lane >> 3) & 7);
    gload16(Ab + (size_t)row * K + kt + gsrc * 8, &As[slot_][r0 * 64]);
  };
  auto stB = [&](int slot_, int r0, int kt) {
    int row = r0 + (lane >> 3);
    int gsrc = (lane & 7) ^ ((lane >> 3) & 7);
    gload16(Bb + (size_t)row * K + kt + gsrc * 8, &Bs[slot_][r0 * 64]);
  };

  const int q2 = w * 2, q4 = w * 4;
  const int rt0 = (q2 < 8 ? 0 : 64) + q2 * 8;
  const int rt1 = (q2 + 1 < 8 ? 0 : 64) + (q2 + 1) * 8;

  {
#pragma unroll
    for (int i = 0; i < 4; ++i) stB(0, (q4 + i) * 8, 0);
    stA(0, rt0, 0); stA(0, 64 + rt0, 0);
    stA(0, rt1, 0); stA(0, 64 + rt1, 0);
#pragma unroll
    for (int i = 0; i < 4; ++i) stB(1, (q4 + i) * 8, 64);
    stA(1, rt0, 64); stA(1, 64 + rt0, 64);
    stA(1, rt1, 64); stA(1, 64 + rt1, 64);
  }
  asm volatile("s_waitcnt vmcnt(8)" ::: "memory");
  __builtin_amdgcn_s_barrier();

  for (int t = 0; t < NT; ++t) {
    const int slot = t & 1;
    const int ns = slot ^ 1;
    const int kt1 = (t + 1) << 6, kt2 = (t + 2) << 6;
    const bool s6 = (t >= 1) && (t + 1 < NT);
    const bool s2 = (t + 2 < NT);

    PHASE32(0,
            { if (s6) { stB(ns, (q4 + 0) * 8, kt1); stB(ns, (q4 + 1) * 8, kt1);
                        stA(ns, 64 + rt0, kt1);     stA(ns, 64 + rt1, kt1); } },
            {});
    PHASE32(1,
            { if (s6) { stB(ns, (q4 + 2) * 8, kt1); stB(ns, (q4 + 3) * 8, kt1); } },
            {});
    PHASE32(2, {}, {});
    PHASE32(3,
            { if (s2) { stA(slot, rt0, kt2); stA(slot, rt1, kt2); } },
            { if (s2) asm volatile("s_waitcnt vmcnt(2)" ::: "memory");
              else    asm volatile("s_waitcnt vmcnt(0)" ::: "memory"); });
  }

  // epilogue: C/D 32x32 layout: col = l31, row = (reg&3) + 8*(reg>>2) + 4*kg
  if constexpr (OM == 2) {
    short* C = (short*)Cv;
#pragma unroll
    for (int mb = 0; mb < 4; ++mb)
#pragma unroll
      for (int nb = 0; nb < 2; ++nb) {
        int rbase = bm * 256 + wr + mb * 32;
        int bb = rbase >> 11, s0 = (rbase & 2047) + 4 * kg;
        int col = bn * 256 + wc + nb * 32 + l31;
#pragma unroll
        for (int rg = 0; rg < 4; ++rg) {
          short4 pk;
          pk.x = f2b(acc[mb][nb][rg * 4 + 0]);
          pk.y = f2b(acc[mb][nb][rg * 4 + 1]);
          pk.z = f2b(acc[mb][nb][rg * 4 + 2]);
          pk.w = f2b(acc[mb][nb][rg * 4 + 3]);
          size_t idx = ((size_t)(bb * 4096 + col)) * 2048 + s0 + rg * 8;
          *reinterpret_cast<short4*>(&C[idx]) = pk;
        }
      }
  } else {
#pragma unroll
    for (int mb = 0; mb < 4; ++mb)
#pragma unroll
      for (int nb = 0; nb < 2; ++nb) {
        int rbase = bm * 256 + wr + mb * 32 + 4 * kg;
        int col = bn * 256 + wc + nb * 32 + l31;
#pragma unroll
        for (int rg = 0; rg < 16; ++rg) {
          int row = rbase + (rg & 3) + 8 * (rg >> 2);
          size_t idx = (size_t)row * N + col;
          if constexpr (OM == 1) ((short*)Cv)[idx] = f2b(acc[mb][nb][rg]);
          else ((float*)Cv)[idx] = acc[mb][nb][rg];
        }
      }
  }
}

// ---------------- fused flash attention + gated prefix, 256 q-rows/block ----------------
// 16 waves x 16 rows, LPT grid. K AND V double-buffered via global_load_lds:
// ONE barrier per tile. Q pre-scaled (rope). Masking only on diag tiles. T13 defer-max.
// LDS: Ks 32K + Vs 32K + Ps 32K = 96 KB.
__global__ __launch_bounds__(1024, 4) void attn_kernel(
    const short* __restrict__ qb, const short* __restrict__ kb, const short* __restrict__ vt,
    const short* __restrict__ pkb, const short* __restrict__ pvt,
    const float* __restrict__ gate, short* __restrict__ ab) {
  __shared__ short Ks[2][64 * 128];
  __shared__ short Vs[2][128 * 64];
  __shared__ short Ps[16][16 * 64];
  const int tid = threadIdx.x;
  const int wave = tid >> 6, lane = tid & 63;
  const int lr = lane & 15, lg = lane >> 4;
  const int lin = blockIdx.x;
  const int qt = 7 - (lin >> 6);     // heavy blocks dispatch first (LPT)
  const int bh = lin & 63;
  const int b = bh >> 5, h = bh & 31;

  bf16x8 aq[4];
  {
    const short* qrow = qb + ((size_t)(b * S_ + qt * 256 + wave * 16 + lr) * H_ + h) * HD_;
#pragma unroll
    for (int kk = 0; kk < 4; ++kk)
      aq[kk] = *reinterpret_cast<const bf16x8*>(qrow + kk * 32 + lg * 8);
  }

  float m = -1e30f, l = 0.f, l2 = 0.f;
  f32x4 o[8] = {}, o2[8] = {};

  const short* kb_bh = kb + ((size_t)b * S_ * H_ + h) * HD_;
  const short* vt_bh = vt + ((size_t)(b * H_ + h)) * HD_ * S_;

  auto stageK = [&](int t, int buf) {
    int row = tid >> 4;
    int col = ((tid & 15) ^ (row & 7)) * 8;
    gload16(kb_bh + (size_t)(t * 64 + row) * (H_ * HD_) + col,
            &Ks[buf][(tid & 960) * 8]);
  };
  auto stagePK = [&](int buf) {
    int row = tid >> 4;
    int col = ((tid & 15) ^ (row & 7)) * 8;
    gload16(pkb + (size_t)row * 4096 + h * HD_ + col, &Ks[buf][(tid & 960) * 8]);
  };
  auto stageV = [&](int t, int buf) {
    int row = tid >> 3;
    int col = ((tid & 7) ^ (row & 7)) * 8;
    gload16(vt_bh + (size_t)row * S_ + t * 64 + col, &Vs[buf][(tid & 1016) * 8]);
  };
  auto stagePV = [&](int buf) {
    int row = tid >> 3;
    int col = ((tid & 7) ^ (row & 7)) * 8;
    gload16(pvt + ((size_t)h * HD_ + row) * 128 + col, &Vs[buf][(tid & 1016) * 8]);
  };

  auto qkt = [&](int buf, f32x4 sc[4]) {
    __builtin_amdgcn_s_setprio(1);
#pragma unroll
    for (int cb = 0; cb < 4; ++cb) {
      int tok = cb * 16 + lr;
#pragma unroll
      for (int kk = 0; kk < 4; ++kk) {
        int addr = tok * 128 + (((kk * 4 + lg) ^ (tok & 7)) * 8);
        bf16x8 bk = *reinterpret_cast<const bf16x8*>(&Ks[buf][addr]);
        sc[cb] = __builtin_amdgcn_mfma_f32_16x16x32_bf16(bk, aq[kk], sc[cb], 0, 0, 0);
      }
    }
    __builtin_amdgcn_s_setprio(0);
  };
  auto pv = [&](int buf, f32x4* acc_) {
#pragma unroll
    for (int kk = 0; kk < 2; ++kk) {
      bf16x8 ap = *reinterpret_cast<const bf16x8*>(
          &Ps[wave][lr * 64 + (((kk * 4 + lg) ^ (lr & 7)) * 8)]);
      __builtin_amdgcn_s_setprio(1);
#pragma unroll
      for (int nb = 0; nb < 8; ++nb) {
        int d = nb * 16 + lr;
        bf16x8 bv = *reinterpret_cast<const bf16x8*>(
            &Vs[buf][d * 64 + (((kk * 4 + lg) ^ (lr & 7)) * 8)]);
        acc_[nb] = __builtin_amdgcn_mfma_f32_16x16x32_bf16(ap, bv, acc_[nb], 0, 0, 0);
      }
      __builtin_amdgcn_s_setprio(0);
    }
  };

  auto process = [&](int t, bool diag) {
    const int buf = t & 1;
    f32x4 sc[4] = {};
    qkt(buf, sc);
    if (diag) {
      const int rowg = qt * 256 + wave * 16 + lr;
#pragma unroll
      for (int cb = 0; cb < 4; ++cb)
#pragma unroll
        for (int j = 0; j < 4; ++j) {
          int colg = t * 64 + cb * 16 + lg * 4 + j;
          if (colg > rowg) sc[cb][j] = -1e30f;
        }
    }
    float mx = sc[0][0];
#pragma unroll
    for (int cb = 0; cb < 4; ++cb)
#pragma unroll
      for (int j = 0; j < 4; ++j) mx = fmaxf(mx, sc[cb][j]);
    mx = fmaxf(mx, __shfl_xor(mx, 16));
    mx = fmaxf(mx, __shfl_xor(mx, 32));
    if (!__all(mx <= m + 8.f)) {
      float mn = fmaxf(m, mx);
      float alpha = __expf(m - mn);
      m = mn;
      l *= alpha;
      f32x4 av;
#pragma unroll
      for (int j = 0; j < 4; ++j) av[j] = __shfl(alpha, lg * 4 + j);
#pragma unroll
      for (int nb = 0; nb < 8; ++nb)
#pragma unroll
        for (int j = 0; j < 4; ++j) o[nb][j] *= av[j];
    }
    float rs = 0.f;
#pragma unroll
    for (int cb = 0; cb < 4; ++cb) {
      short4 pk;
      float p0 = __expf(sc[cb][0] - m);
      float p1 = __expf(sc[cb][1] - m);
      float p2 = __expf(sc[cb][2] - m);
      float p3 = __expf(sc[cb][3] - m);
      rs += (p0 + p1) + (p2 + p3);
      pk.x = f2b(p0); pk.y = f2b(p1); pk.z = f2b(p2); pk.w = f2b(p3);
      int gran = (cb * 2 + (lg >> 1)) ^ (lr & 7);
      *reinterpret_cast<short4*>(&Ps[wave][lr * 64 + gran * 8 + (lg & 1) * 4]) = pk;
    }
    rs += __shfl_xor(rs, 16);
    rs += __shfl_xor(rs, 32);
    l += rs;
    pv(buf, o);
  };

  auto processPrefix = [&]() {
    f32x4 sc[4] = {};
    qkt(0, sc);
#pragma unroll
    for (int cb = 0; cb < 4; ++cb)
#pragma unroll
      for (int j = 0; j < 4; ++j) {
        int coll = cb * 16 + lg * 4 + j;
        if (coll >= P_) sc[cb][j] = -1e30f;
      }
    float mx = sc[0][0];
#pragma unroll
    for (int cb = 0; cb < 4; ++cb)
#pragma unroll
      for (int j = 0; j < 4; ++j) mx = fmaxf(mx, sc[cb][j]);
    mx = fmaxf(mx, __shfl_xor(mx, 16));
    mx = fmaxf(mx, __shfl_xor(mx, 32));
    float rs = 0.f;
#pragma unroll
    for (int cb = 0; cb < 4; ++cb) {
      short4 pk;
      float p0 = __expf(sc[cb][0] - mx);
      float p1 = __expf(sc[cb][1] - mx);
      float p2 = __expf(sc[cb][2] - mx);
      float p3 = __expf(sc[cb][3] - mx);
      rs += (p0 + p1) + (p2 + p3);
      pk.x = f2b(p0); pk.y = f2b(p1); pk.z = f2b(p2); pk.w = f2b(p3);
      int gran = (cb * 2 + (lg >> 1)) ^ (lr & 7);
      *reinterpret_cast<short4*>(&Ps[wave][lr * 64 + gran * 8 + (lg & 1) * 4]) = pk;
    }
    rs += __shfl_xor(rs, 16);
    rs += __shfl_xor(rs, 32);
    l2 = rs;
    pv(0, o2);
  };

  const int nt = 4 * (qt + 1);

  stagePK(0);
  stagePV(0);
  __syncthreads();
  processPrefix();
  __syncthreads();

  stageK(0, 0);
  stageV(0, 0);
  __syncthreads();
  for (int t = 0; t < nt; ++t) {
    if (t + 1 < nt) {
      stageK(t + 1, (t + 1) & 1);
      stageV(t + 1, (t + 1) & 1);
    }
    process(t, t >= 4 * qt);
    __syncthreads();
  }

  {
    float g = tanhf(gate[h]);
    f32x4 lv, lv2;
#pragma unroll
    for (int j = 0; j < 4; ++j) {
      lv[j] = __shfl(l, lg * 4 + j);
      lv2[j] = __shfl(l2, lg * 4 + j);
    }
#pragma unroll
    for (int j = 0; j < 4; ++j) {
      int q = qt * 256 + wave * 16 + lg * 4 + j;
      float inv = 1.f / lv[j];
      float inv2 = g / lv2[j];
      size_t base = ((size_t)(b * S_ + q) * H_ + h) * HD_;
#pragma unroll
      for (int nb = 0; nb < 8; ++nb)
        ab[base + nb * 16 + lr] = f2b(o[nb][j] * inv + o2[nb][j] * inv2);
    }
  }
}

// ---------------- launcher ----------------
extern "C" void kernel_launch(void* const* d_in, const int* in_sizes, int n_in,
                              void* d_out, int out_size, void* d_ws, size_t ws_size,
                              hipStream_t stream) {
  const float* x = (const float*)d_in[0];
  const float* fc = (const float*)d_in[1];
  const float* fs = (const float*)d_in[2];
  const float* prefix = (const float*)d_in[3];
  const float* gate = (const float*)d_in[4];
  const float* wq = (const float*)d_in[5];
  const float* wk = (const float*)d_in[6];
  const float* wv = (const float*)d_in[7];
  const float* wo = (const float*)d_in[8];
  float* out = (float*)d_out;

  char* ws = (char*)d_ws;
  const size_t SZ = (size_t)4096 * 4096 * 2;
  short* xb = (short*)(ws);
  short* wT = (short*)(ws + SZ);
  short* qbuf = (short*)(ws + 2 * SZ);
  short* kbuf = (short*)(ws + 3 * SZ);
  short* vT = (short*)(ws + 4 * SZ);
  short* pb = (short*)(ws + 5 * SZ);
  short* pkb = (short*)(ws + 5 * SZ + (1 << 20));
  short* pvt = (short*)(ws + 5 * SZ + (2 << 20));
  short* abuf = xb;  // alias: x_bf16 dead after V projection

  dim3 tcg(128, 128), tcb(32, 8);
  dim3 gg(16, 16), gp(32, 1);

  convert_f32_bf16<<<16384, 256, 0, stream>>>(x, xb);
  pad_prefix<<<2048, 256, 0, stream>>>(prefix, pb);

  transpose_convert<<<tcg, tcb, 0, stream>>>(wq, wT, 4096, 4096);
  gemm256<1><<<gg, 512, 0, stream>>>(xb, wT, qbuf, 4096, 4096, 4096);

  transpose_convert<<<tcg, tcb, 0, stream>>>(wk, wT, 4096, 4096);
  gemm256<1><<<gg, 512, 0, stream>>>(xb, wT, kbuf, 4096, 4096, 4096);
  gemm_bt<1><<<gp, 256, 0, stream>>>(pb, wT, pkb, 128, 4096, 4096);

  transpose_convert<<<tcg, tcb, 0, stream>>>(wv, wT, 4096, 4096);
  gemm256<2><<<gg, 512, 0, stream>>>(xb, wT, vT, 4096, 4096, 4096);
  gemm_bt<3><<<gp, 256, 0, stream>>>(pb, wT, pvt, 128, 4096, 4096);

  rope_kernel<<<dim3(8192, 2), 256, 0, stream>>>(qbuf, kbuf, fc, fs);

  attn_kernel<<<512, 1024, 0, stream>>>(qbuf, kbuf, vT, pkb, pvt, gate, abuf);

  transpose_convert<<<tcg, tcb, 0, stream>>>(wo, wT, 4096, 4096);
  gemm256<0><<<gg, 512, 0, stream>>>(abuf, wT, out, 4096, 4096, 4096);
}

// Round 17
// 867.763 us; speedup vs baseline: 1.0657x; 1.0574x over previous
//
#include <hip/hip_runtime.h>
#include <hip/hip_bf16.h>

#define AS1 __attribute__((address_space(1)))
#define AS3 __attribute__((address_space(3)))

typedef __attribute__((ext_vector_type(8))) short bf16x8;
typedef __attribute__((ext_vector_type(4))) float f32x4;

#define B_ 2
#define S_ 2048
#define D_ 4096
#define H_ 32
#define HD_ 128
#define P_ 30

__device__ __forceinline__ short f2b(float f) {
  union { __hip_bfloat16 h; short s; } u;
  u.h = __float2bfloat16(f);
  return u.s;
}
__device__ __forceinline__ float b2f(short s) {
  union { short s; __hip_bfloat16 h; } u;
  u.s = s;
  return __bfloat162float(u.h);
}
__device__ __forceinline__ void gload16(const void* g, void* l) {
  __builtin_amdgcn_global_load_lds((const AS1 void*)g, (AS3 void*)l, 16, 0, 0);
}

// ---------------- elementwise conversion ----------------
__global__ __launch_bounds__(256) void convert_f32_bf16(const float* __restrict__ in,
                                                        short* __restrict__ out) {
  size_t i = ((size_t)blockIdx.x * 256 + threadIdx.x) * 4;
  float4 v = *reinterpret_cast<const float4*>(in + i);
  short4 o;
  o.x = f2b(v.x); o.y = f2b(v.y); o.z = f2b(v.z); o.w = f2b(v.w);
  *reinterpret_cast<short4*>(out + i) = o;
}

// prefix (30 x 4096 f32) -> padded 128 x 4096 bf16 (zeros beyond row 29)
__global__ __launch_bounds__(256) void pad_prefix(const float* __restrict__ p,
                                                  short* __restrict__ pb) {
  int i = blockIdx.x * 256 + threadIdx.x;
  int row = i >> 12, col = i & 4095;
  pb[i] = (row < P_) ? f2b(p[row * D_ + col]) : (short)0;
}

// W (K x N) f32 -> Wt (N x K) bf16, 64x64 tiles, float4 loads / short4 stores
__global__ __launch_bounds__(256) void transpose_convert(const float* __restrict__ W,
                                                         short* __restrict__ Wt,
                                                         int K, int N) {
  __shared__ float t[64][65];
  const int bx = blockIdx.x, by = blockIdx.y;
  const int tid = threadIdx.x;
  const int r = tid >> 4;        // 0..15
  const int c4 = tid & 15;       // float4 column 0..15
#pragma unroll
  for (int i = 0; i < 4; ++i) {
    int row = r + i * 16;
    float4 v = *reinterpret_cast<const float4*>(
        &W[(size_t)(by * 64 + row) * N + bx * 64 + c4 * 4]);
    t[row][c4 * 4 + 0] = v.x; t[row][c4 * 4 + 1] = v.y;
    t[row][c4 * 4 + 2] = v.z; t[row][c4 * 4 + 3] = v.w;
  }
  __syncthreads();
#pragma unroll
  for (int i = 0; i < 4; ++i) {
    int on = r + i * 16;  // output row (= original col block offset)
    short4 pk;
    pk.x = f2b(t[c4 * 4 + 0][on]);
    pk.y = f2b(t[c4 * 4 + 1][on]);
    pk.z = f2b(t[c4 * 4 + 2][on]);
    pk.w = f2b(t[c4 * 4 + 3][on]);
    *reinterpret_cast<short4*>(&Wt[(size_t)(bx * 64 + on) * K + by * 64 + c4 * 4]) = pk;
  }
}

// in-place RoPE on (B,S,H,HD) bf16; blockIdx.y selects q/k buffer.
// q is pre-scaled by 1/sqrt(HD) (folded attention scale).
__global__ __launch_bounds__(256) void rope_kernel(short* __restrict__ q,
                                                   short* __restrict__ k,
                                                   const float* __restrict__ fc,
                                                   const float* __restrict__ fs) {
  short* t = blockIdx.y ? k : q;
  const float qs = blockIdx.y ? 1.0f : 0.08838834764831845f;
  size_t g = ((size_t)blockIdx.x * 256 + threadIdx.x) * 8;
  int d = (int)(g & 127);
  int s = (int)((g >> 12) & 2047);
  bf16x8 v = *reinterpret_cast<bf16x8*>(t + g);
  int i0 = d >> 1;
  float4 c = *reinterpret_cast<const float4*>(fc + (size_t)s * 64 + i0);
  float4 sn = *reinterpret_cast<const float4*>(fs + (size_t)s * 64 + i0);
  float cc[4] = {c.x, c.y, c.z, c.w};
  float ss[4] = {sn.x, sn.y, sn.z, sn.w};
  bf16x8 o;
#pragma unroll
  for (int p = 0; p < 4; ++p) {
    float t0 = b2f(v[2 * p]), t1 = b2f(v[2 * p + 1]);
    o[2 * p] = f2b((t0 * cc[p] - t1 * ss[p]) * qs);
    o[2 * p + 1] = f2b((t0 * ss[p] + t1 * cc[p]) * qs);
  }
  *reinterpret_cast<bf16x8*>(t + g) = o;
}

// ---------------- small GEMM (m97 structure) for prefix projections ----------------
// OM: 1 = bf16 out (MxN), 3 = bf16 transposed out (C^T, N x M layout)
template <int OM>
__global__ __launch_bounds__(256) void gemm_bt(const short* __restrict__ A,
                                               const short* __restrict__ Bt,
                                               void* __restrict__ Cv,
                                               int M, int N, int K) {
  __shared__ short As[128 * 32];
  __shared__ short Bs[128 * 32];
  const int tid = threadIdx.x;
  const int lane = tid & 63;
  const int wbase = tid & 192;
  const int wr = ((tid >> 7) & 1) * 64;
  const int wc = ((tid >> 6) & 1) * 64;
  const int lr = lane & 15;
  const int lk = (lane >> 4) * 8;
  int lin = blockIdx.y * gridDim.x + blockIdx.x;
  int nwg = gridDim.x * gridDim.y;
  int cpx = nwg >> 3;
  int swz = (lin & 7) * cpx + (lin >> 3);
  const int bm = swz / gridDim.x, bn = swz % gridDim.x;
  f32x4 acc[4][4] = {};
  const short* Ab = A + (size_t)bm * 128 * K;
  const short* Bb = Bt + (size_t)bn * 128 * K;
  for (int kt = 0; kt < K; kt += 32) {
    __syncthreads();
#pragma unroll
    for (int i = 0; i < 2; ++i) {
      int f = i * 256 + tid;
      int row = f >> 2, col = (f & 3) * 8;
      gload16(Ab + (size_t)row * K + kt + col, &As[(i * 256 + wbase) * 8]);
      gload16(Bb + (size_t)row * K + kt + col, &Bs[(i * 256 + wbase) * 8]);
    }
    __syncthreads();
    bf16x8 af[4], bfr[4];
#pragma unroll
    for (int m = 0; m < 4; ++m)
      af[m] = *reinterpret_cast<const bf16x8*>(&As[(wr + m * 16 + lr) * 32 + lk]);
#pragma unroll
    for (int n = 0; n < 4; ++n)
      bfr[n] = *reinterpret_cast<const bf16x8*>(&Bs[(wc + n * 16 + lr) * 32 + lk]);
#pragma unroll
    for (int m = 0; m < 4; ++m)
#pragma unroll
      for (int n = 0; n < 4; ++n)
        acc[m][n] = __builtin_amdgcn_mfma_f32_16x16x32_bf16(af[m], bfr[n], acc[m][n], 0, 0, 0);
  }
  const int row0 = bm * 128 + wr + (lane >> 4) * 4;
  const int col0 = bn * 128 + wc + lr;
  if constexpr (OM == 3) {
    short* C = (short*)Cv;
#pragma unroll
    for (int m = 0; m < 4; ++m)
#pragma unroll
      for (int n = 0; n < 4; ++n) {
        short4 pk;
        pk.x = f2b(acc[m][n][0]); pk.y = f2b(acc[m][n][1]);
        pk.z = f2b(acc[m][n][2]); pk.w = f2b(acc[m][n][3]);
        size_t idx = (size_t)(col0 + n * 16) * M + row0 + m * 16;
        *reinterpret_cast<short4*>(&C[idx]) = pk;
      }
  } else {
#pragma unroll
    for (int m = 0; m < 4; ++m)
#pragma unroll
      for (int n = 0; n < 4; ++n)
#pragma unroll
        for (int j = 0; j < 4; ++j) {
          size_t idx = (size_t)(row0 + m * 16 + j) * N + col0 + n * 16;
          ((short*)Cv)[idx] = f2b(acc[m][n][j]);
        }
  }
}

// ---------------- 256x256 8-wave GEMM, kh-major 4-phase, B-frag register reuse ----------------
// (v14 verified: 139 us, MfmaUtil 42%, 0 conflicts)
#define MFMA16(mh)                                                              \
  _Pragma("unroll") for (int mm = 0; mm < 4; ++mm)                              \
    _Pragma("unroll") for (int nn = 0; nn < 4; ++nn)                            \
      acc[(mh)*4 + mm][nn] = __builtin_amdgcn_mfma_f32_16x16x32_bf16(           \
          af[mm], bf[nn], acc[(mh)*4 + mm][nn], 0, 0, 0);

#define PH_SYNC_PRE                                                             \
  __builtin_amdgcn_s_barrier();                                                 \
  asm volatile("s_waitcnt lgkmcnt(0)" ::: "memory");                            \
  __builtin_amdgcn_sched_barrier(0);                                            \
  __builtin_amdgcn_s_setprio(1);

#define PH_SYNC_POST                                                            \
  __builtin_amdgcn_s_setprio(0);                                                \
  __builtin_amdgcn_s_barrier();

template <int OM>
__global__ __launch_bounds__(512, 2) void gemm256(const short* __restrict__ A,
                                                  const short* __restrict__ Bt,
                                                  void* __restrict__ Cv,
                                                  int M, int N, int K) {
  __shared__ short As[2][256 * 64];
  __shared__ short Bs[2][256 * 64];
  const int tid = threadIdx.x;
  const int w = tid >> 6;
  const int lane = tid & 63;
  const int lr = lane & 15, lg = lane >> 4;
  const int wr = (w >> 2) * 128;
  const int wc = (w & 3) * 64;
  int lin = blockIdx.y * gridDim.x + blockIdx.x;
  int nwg = gridDim.x * gridDim.y;
  int cpx = nwg >> 3;
  int swz = (lin & 7) * cpx + (lin >> 3);
  const int bm = swz / gridDim.x, bn = swz % gridDim.x;

  const short* Ab = A + (size_t)bm * 256 * K;
  const short* Bb = Bt + (size_t)bn * 256 * K;
  const int NT = K >> 6;

  f32x4 acc[8][4] = {};

  auto stA = [&](int slot_, int r0, int kt) {
    int row = r0 + (lane >> 3);
    int gsrc = (lane & 7) ^ ((lane >> 3) & 7);
    gload16(Ab + (size_t)row * K + kt + gsrc * 8, &As[slot_][r0 * 64]);
  };
  auto stB = [&](int slot_, int r0, int kt) {
    int row = r0 + (lane >> 3);
    int gsrc = (lane & 7) ^ ((lane >> 3) & 7);
    gload16(Bb + (size_t)row * K + kt + gsrc * 8, &Bs[slot_][r0 * 64]);
  };

  const int q2 = w * 2, q4 = w * 4;
  const int rt0 = (q2 < 8 ? 0 : 64) + q2 * 8;
  const int rt1 = (q2 + 1 < 8 ? 0 : 64) + (q2 + 1) * 8;

  {
#pragma unroll
    for (int i = 0; i < 4; ++i) stB(0, (q4 + i) * 8, 0);
    stA(0, rt0, 0); stA(0, 64 + rt0, 0);
    stA(0, rt1, 0); stA(0, 64 + rt1, 0);
#pragma unroll
    for (int i = 0; i < 4; ++i) stB(1, (q4 + i) * 8, 64);
    stA(1, rt0, 64); stA(1, 64 + rt0, 64);
    stA(1, rt1, 64); stA(1, 64 + rt1, 64);
  }
  asm volatile("s_waitcnt vmcnt(8)" ::: "memory");
  __builtin_amdgcn_s_barrier();

  for (int t = 0; t < NT; ++t) {
    const int slot = t & 1;
    const int ns = slot ^ 1;
    const int kt1 = (t + 1) << 6, kt2 = (t + 2) << 6;
    const bool s6 = (t >= 1) && (t + 1 < NT);
    const bool s2 = (t + 2 < NT);
    bf16x8 bf[4], af[4];

    // P1: kh=0, mh=0 — read B(kh0) + A-top(kh0); stage B01(t+1) + A-bottom(t+1)
    {
      const int pg = (lg ^ (lr & 7)) * 8;
#pragma unroll
      for (int nn = 0; nn < 4; ++nn)
        bf[nn] = *(const bf16x8*)&Bs[slot][(wc + nn * 16 + lr) * 64 + pg];
#pragma unroll
      for (int mm = 0; mm < 4; ++mm)
        af[mm] = *(const bf16x8*)&As[slot][(wr + mm * 16 + lr) * 64 + pg];
      if (s6) { stB(ns, (q4 + 0) * 8, kt1); stB(ns, (q4 + 1) * 8, kt1);
                stA(ns, 64 + rt0, kt1);     stA(ns, 64 + rt1, kt1); }
      PH_SYNC_PRE
      MFMA16(0)
      PH_SYNC_POST
    }
    // P2: kh=0, mh=1 — read A-bottom(kh0), reuse bf; stage B23(t+1)
    {
      const int pg = (lg ^ (lr & 7)) * 8;
#pragma unroll
      for (int mm = 0; mm < 4; ++mm)
        af[mm] = *(const bf16x8*)&As[slot][(wr + 64 + mm * 16 + lr) * 64 + pg];
      if (s6) { stB(ns, (q4 + 2) * 8, kt1); stB(ns, (q4 + 3) * 8, kt1); }
      PH_SYNC_PRE
      MFMA16(1)
      PH_SYNC_POST
    }
    // P3: kh=1, mh=0 — read B(kh1) + A-top(kh1)
    {
      const int pg = ((4 + lg) ^ (lr & 7)) * 8;
#pragma unroll
      for (int nn = 0; nn < 4; ++nn)
        bf[nn] = *(const bf16x8*)&Bs[slot][(wc + nn * 16 + lr) * 64 + pg];
#pragma unroll
      for (int mm = 0; mm < 4; ++mm)
        af[mm] = *(const bf16x8*)&As[slot][(wr + mm * 16 + lr) * 64 + pg];
      PH_SYNC_PRE
      MFMA16(0)
      PH_SYNC_POST
    }
    // P4: kh=1, mh=1 — read A-bottom(kh1), reuse bf; stage A-top(t+2); TAIL vmcnt
    {
      const int pg = ((4 + lg) ^ (lr & 7)) * 8;
#pragma unroll
      for (int mm = 0; mm < 4; ++mm)
        af[mm] = *(const bf16x8*)&As[slot][(wr + 64 + mm * 16 + lr) * 64 + pg];
      if (s2) { stA(slot, rt0, kt2); stA(slot, rt1, kt2); }
      PH_SYNC_PRE
      MFMA16(1)
      __builtin_amdgcn_s_setprio(0);
      if (s2) asm volatile("s_waitcnt vmcnt(2)" ::: "memory");
      else    asm volatile("s_waitcnt vmcnt(0)" ::: "memory");
      __builtin_amdgcn_s_barrier();
    }
  }

  const int row0 = bm * 256 + wr + lg * 4;
  const int col0 = bn * 256 + wc + lr;
  if constexpr (OM == 2) {
    short* C = (short*)Cv;
#pragma unroll
    for (int mf = 0; mf < 8; ++mf)
#pragma unroll
      for (int n = 0; n < 4; ++n) {
        int r0 = row0 + mf * 16;
        int bb = r0 >> 11, s0 = r0 & 2047;
        short4 pk;
        pk.x = f2b(acc[mf][n][0]); pk.y = f2b(acc[mf][n][1]);
        pk.z = f2b(acc[mf][n][2]); pk.w = f2b(acc[mf][n][3]);
        size_t idx = ((size_t)(bb * 4096 + col0 + n * 16)) * 2048 + s0;
        *reinterpret_cast<short4*>(&C[idx]) = pk;
      }
  } else {
#pragma unroll
    for (int mf = 0; mf < 8; ++mf)
#pragma unroll
      for (int n = 0; n < 4; ++n)
#pragma unroll
        for (int j = 0; j < 4; ++j) {
          size_t idx = (size_t)(row0 + mf * 16 + j) * N + col0 + n * 16;
          if constexpr (OM == 1) ((short*)Cv)[idx] = f2b(acc[mf][n][j]);
          else ((float*)Cv)[idx] = acc[mf][n][j];
        }
  }
}

// ---------------- fused flash attention + gated prefix, 256 q-rows/block ----------------
// 16 waves x 16 rows, LPT grid. K AND V double-buffered via global_load_lds:
// ONE barrier per tile. Q pre-scaled (rope). Masking only on diag tiles. T13 defer-max.
// LDS: Ks 32K + Vs 32K + Ps 32K = 96 KB.
__global__ __launch_bounds__(1024, 4) void attn_kernel(
    const short* __restrict__ qb, const short* __restrict__ kb, const short* __restrict__ vt,
    const short* __restrict__ pkb, const short* __restrict__ pvt,
    const float* __restrict__ gate, short* __restrict__ ab) {
  __shared__ short Ks[2][64 * 128];
  __shared__ short Vs[2][128 * 64];
  __shared__ short Ps[16][16 * 64];
  const int tid = threadIdx.x;
  const int wave = tid >> 6, lane = tid & 63;
  const int lr = lane & 15, lg = lane >> 4;
  const int lin = blockIdx.x;
  const int qt = 7 - (lin >> 6);     // heavy blocks dispatch first (LPT)
  const int bh = lin & 63;
  const int b = bh >> 5, h = bh & 31;

  bf16x8 aq[4];
  {
    const short* qrow = qb + ((size_t)(b * S_ + qt * 256 + wave * 16 + lr) * H_ + h) * HD_;
#pragma unroll
    for (int kk = 0; kk < 4; ++kk)
      aq[kk] = *reinterpret_cast<const bf16x8*>(qrow + kk * 32 + lg * 8);
  }

  float m = -1e30f, l = 0.f, l2 = 0.f;
  f32x4 o[8] = {}, o2[8] = {};

  const short* kb_bh = kb + ((size_t)b * S_ * H_ + h) * HD_;
  const short* vt_bh = vt + ((size_t)(b * H_ + h)) * HD_ * S_;

  auto stageK = [&](int t, int buf) {
    int row = tid >> 4;
    int col = ((tid & 15) ^ (row & 7)) * 8;
    gload16(kb_bh + (size_t)(t * 64 + row) * (H_ * HD_) + col,
            &Ks[buf][(tid & 960) * 8]);
  };
  auto stagePK = [&](int buf) {
    int row = tid >> 4;
    int col = ((tid & 15) ^ (row & 7)) * 8;
    gload16(pkb + (size_t)row * 4096 + h * HD_ + col, &Ks[buf][(tid & 960) * 8]);
  };
  auto stageV = [&](int t, int buf) {
    int row = tid >> 3;
    int col = ((tid & 7) ^ (row & 7)) * 8;
    gload16(vt_bh + (size_t)row * S_ + t * 64 + col, &Vs[buf][(tid & 1016) * 8]);
  };
  auto stagePV = [&](int buf) {
    int row = tid >> 3;
    int col = ((tid & 7) ^ (row & 7)) * 8;
    gload16(pvt + ((size_t)h * HD_ + row) * 128 + col, &Vs[buf][(tid & 1016) * 8]);
  };

  auto qkt = [&](int buf, f32x4 sc[4]) {
    __builtin_amdgcn_s_setprio(1);
#pragma unroll
    for (int cb = 0; cb < 4; ++cb) {
      int tok = cb * 16 + lr;
#pragma unroll
      for (int kk = 0; kk < 4; ++kk) {
        int addr = tok * 128 + (((kk * 4 + lg) ^ (tok & 7)) * 8);
        bf16x8 bk = *reinterpret_cast<const bf16x8*>(&Ks[buf][addr]);
        sc[cb] = __builtin_amdgcn_mfma_f32_16x16x32_bf16(bk, aq[kk], sc[cb], 0, 0, 0);
      }
    }
    __builtin_amdgcn_s_setprio(0);
  };
  auto pv = [&](int buf, f32x4* acc_) {
#pragma unroll
    for (int kk = 0; kk < 2; ++kk) {
      bf16x8 ap = *reinterpret_cast<const bf16x8*>(
          &Ps[wave][lr * 64 + (((kk * 4 + lg) ^ (lr & 7)) * 8)]);
      __builtin_amdgcn_s_setprio(1);
#pragma unroll
      for (int nb = 0; nb < 8; ++nb) {
        int d = nb * 16 + lr;
        bf16x8 bv = *reinterpret_cast<const bf16x8*>(
            &Vs[buf][d * 64 + (((kk * 4 + lg) ^ (lr & 7)) * 8)]);
        acc_[nb] = __builtin_amdgcn_mfma_f32_16x16x32_bf16(ap, bv, acc_[nb], 0, 0, 0);
      }
      __builtin_amdgcn_s_setprio(0);
    }
  };

  auto process = [&](int t, bool diag) {
    const int buf = t & 1;
    f32x4 sc[4] = {};
    qkt(buf, sc);
    if (diag) {
      const int rowg = qt * 256 + wave * 16 + lr;
#pragma unroll
      for (int cb = 0; cb < 4; ++cb)
#pragma unroll
        for (int j = 0; j < 4; ++j) {
          int colg = t * 64 + cb * 16 + lg * 4 + j;
          if (colg > rowg) sc[cb][j] = -1e30f;
        }
    }
    float mx = sc[0][0];
#pragma unroll
    for (int cb = 0; cb < 4; ++cb)
#pragma unroll
      for (int j = 0; j < 4; ++j) mx = fmaxf(mx, sc[cb][j]);
    mx = fmaxf(mx, __shfl_xor(mx, 16));
    mx = fmaxf(mx, __shfl_xor(mx, 32));
    if (!__all(mx <= m + 8.f)) {
      float mn = fmaxf(m, mx);
      float alpha = __expf(m - mn);
      m = mn;
      l *= alpha;
      f32x4 av;
#pragma unroll
      for (int j = 0; j < 4; ++j) av[j] = __shfl(alpha, lg * 4 + j);
#pragma unroll
      for (int nb = 0; nb < 8; ++nb)
#pragma unroll
        for (int j = 0; j < 4; ++j) o[nb][j] *= av[j];
    }
    float rs = 0.f;
#pragma unroll
    for (int cb = 0; cb < 4; ++cb) {
      short4 pk;
      float p0 = __expf(sc[cb][0] - m);
      float p1 = __expf(sc[cb][1] - m);
      float p2 = __expf(sc[cb][2] - m);
      float p3 = __expf(sc[cb][3] - m);
      rs += (p0 + p1) + (p2 + p3);
      pk.x = f2b(p0); pk.y = f2b(p1); pk.z = f2b(p2); pk.w = f2b(p3);
      int gran = (cb * 2 + (lg >> 1)) ^ (lr & 7);
      *reinterpret_cast<short4*>(&Ps[wave][lr * 64 + gran * 8 + (lg & 1) * 4]) = pk;
    }
    rs += __shfl_xor(rs, 16);
    rs += __shfl_xor(rs, 32);
    l += rs;
    pv(buf, o);
  };

  auto processPrefix = [&]() {
    f32x4 sc[4] = {};
    qkt(0, sc);
#pragma unroll
    for (int cb = 0; cb < 4; ++cb)
#pragma unroll
      for (int j = 0; j < 4; ++j) {
        int coll = cb * 16 + lg * 4 + j;
        if (coll >= P_) sc[cb][j] = -1e30f;
      }
    float mx = sc[0][0];
#pragma unroll
    for (int cb = 0; cb < 4; ++cb)
#pragma unroll
      for (int j = 0; j < 4; ++j) mx = fmaxf(mx, sc[cb][j]);
    mx = fmaxf(mx, __shfl_xor(mx, 16));
    mx = fmaxf(mx, __shfl_xor(mx, 32));
    float rs = 0.f;
#pragma unroll
    for (int cb = 0; cb < 4; ++cb) {
      short4 pk;
      float p0 = __expf(sc[cb][0] - mx);
      float p1 = __expf(sc[cb][1] - mx);
      float p2 = __expf(sc[cb][2] - mx);
      float p3 = __expf(sc[cb][3] - mx);
      rs += (p0 + p1) + (p2 + p3);
      pk.x = f2b(p0); pk.y = f2b(p1); pk.z = f2b(p2); pk.w = f2b(p3);
      int gran = (cb * 2 + (lg >> 1)) ^ (lr & 7);
      *reinterpret_cast<short4*>(&Ps[wave][lr * 64 + gran * 8 + (lg & 1) * 4]) = pk;
    }
    rs += __shfl_xor(rs, 16);
    rs += __shfl_xor(rs, 32);
    l2 = rs;
    pv(0, o2);
  };

  const int nt = 4 * (qt + 1);

  stagePK(0);
  stagePV(0);
  __syncthreads();
  processPrefix();
  __syncthreads();

  stageK(0, 0);
  stageV(0, 0);
  __syncthreads();
  for (int t = 0; t < nt; ++t) {
    if (t + 1 < nt) {
      stageK(t + 1, (t + 1) & 1);
      stageV(t + 1, (t + 1) & 1);
    }
    process(t, t >= 4 * qt);
    __syncthreads();
  }

  {
    float g = tanhf(gate[h]);
    f32x4 lv, lv2;
#pragma unroll
    for (int j = 0; j < 4; ++j) {
      lv[j] = __shfl(l, lg * 4 + j);
      lv2[j] = __shfl(l2, lg * 4 + j);
    }
#pragma unroll
    for (int j = 0; j < 4; ++j) {
      int q = qt * 256 + wave * 16 + lg * 4 + j;
      float inv = 1.f / lv[j];
      float inv2 = g / lv2[j];
      size_t base = ((size_t)(b * S_ + q) * H_ + h) * HD_;
#pragma unroll
      for (int nb = 0; nb < 8; ++nb)
        ab[base + nb * 16 + lr] = f2b(o[nb][j] * inv + o2[nb][j] * inv2);
    }
  }
}

// ---------------- launcher ----------------
extern "C" void kernel_launch(void* const* d_in, const int* in_sizes, int n_in,
                              void* d_out, int out_size, void* d_ws, size_t ws_size,
                              hipStream_t stream) {
  const float* x = (const float*)d_in[0];
  const float* fc = (const float*)d_in[1];
  const float* fs = (const float*)d_in[2];
  const float* prefix = (const float*)d_in[3];
  const float* gate = (const float*)d_in[4];
  const float* wq = (const float*)d_in[5];
  const float* wk = (const float*)d_in[6];
  const float* wv = (const float*)d_in[7];
  const float* wo = (const float*)d_in[8];
  float* out = (float*)d_out;

  char* ws = (char*)d_ws;
  const size_t SZ = (size_t)4096 * 4096 * 2;
  short* xb = (short*)(ws);
  short* wT = (short*)(ws + SZ);
  short* qbuf = (short*)(ws + 2 * SZ);
  short* kbuf = (short*)(ws + 3 * SZ);
  short* vT = (short*)(ws + 4 * SZ);
  short* pb = (short*)(ws + 5 * SZ);
  short* pkb = (short*)(ws + 5 * SZ + (1 << 20));
  short* pvt = (short*)(ws + 5 * SZ + (2 << 20));
  short* abuf = xb;  // alias: x_bf16 dead after V projection

  dim3 tcg(64, 64), tcb(256);
  dim3 gg(16, 16), gp(32, 1);

  convert_f32_bf16<<<16384, 256, 0, stream>>>(x, xb);
  pad_prefix<<<2048, 256, 0, stream>>>(prefix, pb);

  transpose_convert<<<tcg, tcb, 0, stream>>>(wq, wT, 4096, 4096);
  gemm256<1><<<gg, 512, 0, stream>>>(xb, wT, qbuf, 4096, 4096, 4096);

  transpose_convert<<<tcg, tcb, 0, stream>>>(wk, wT, 4096, 4096);
  gemm256<1><<<gg, 512, 0, stream>>>(xb, wT, kbuf, 4096, 4096, 4096);
  gemm_bt<1><<<gp, 256, 0, stream>>>(pb, wT, pkb, 128, 4096, 4096);

  transpose_convert<<<tcg, tcb, 0, stream>>>(wv, wT, 4096, 4096);
  gemm256<2><<<gg, 512, 0, stream>>>(xb, wT, vT, 4096, 4096, 4096);
  gemm_bt<3><<<gp, 256, 0, stream>>>(pb, wT, pvt, 128, 4096, 4096);

  rope_kernel<<<dim3(8192, 2), 256, 0, stream>>>(qbuf, kbuf, fc, fs);

  attn_kernel<<<512, 1024, 0, stream>>>(qbuf, kbuf, vT, pkb, pvt, gate, abuf);

  transpose_convert<<<tcg, tcb, 0, stream>>>(wo, wT, 4096, 4096);
  gemm256<0><<<gg, 512, 0, stream>>>(abuf, wT, out, 4096, 4096, 4096);
}

// Round 18
// 859.036 us; speedup vs baseline: 1.0765x; 1.0102x over previous
//
#include <hip/hip_runtime.h>
#include <hip/hip_bf16.h>

#define AS1 __attribute__((address_space(1)))
#define AS3 __attribute__((address_space(3)))

typedef __attribute__((ext_vector_type(8))) short bf16x8;
typedef __attribute__((ext_vector_type(4))) float f32x4;

#define B_ 2
#define S_ 2048
#define D_ 4096
#define H_ 32
#define HD_ 128
#define P_ 30

__device__ __forceinline__ short f2b(float f) {
  union { __hip_bfloat16 h; short s; } u;
  u.h = __float2bfloat16(f);
  return u.s;
}
__device__ __forceinline__ float b2f(short s) {
  union { short s; __hip_bfloat16 h; } u;
  u.s = s;
  return __bfloat162float(u.h);
}
__device__ __forceinline__ void gload16(const void* g, void* l) {
  __builtin_amdgcn_global_load_lds((const AS1 void*)g, (AS3 void*)l, 16, 0, 0);
}

// ---------------- elementwise conversion ----------------
__global__ __launch_bounds__(256) void convert_f32_bf16(const float* __restrict__ in,
                                                        short* __restrict__ out) {
  size_t i = ((size_t)blockIdx.x * 256 + threadIdx.x) * 4;
  float4 v = *reinterpret_cast<const float4*>(in + i);
  short4 o;
  o.x = f2b(v.x); o.y = f2b(v.y); o.z = f2b(v.z); o.w = f2b(v.w);
  *reinterpret_cast<short4*>(out + i) = o;
}

// prefix (30 x 4096 f32) -> padded 128 x 4096 bf16 (zeros beyond row 29)
__global__ __launch_bounds__(256) void pad_prefix(const float* __restrict__ p,
                                                  short* __restrict__ pb) {
  int i = blockIdx.x * 256 + threadIdx.x;
  int row = i >> 12, col = i & 4095;
  pb[i] = (row < P_) ? f2b(p[row * D_ + col]) : (short)0;
}

// W (K x N) f32 -> Wt (N x K) bf16, 64x64 tiles, float4 loads / short4 stores
__global__ __launch_bounds__(256) void transpose_convert(const float* __restrict__ W,
                                                         short* __restrict__ Wt,
                                                         int K, int N) {
  __shared__ float t[64][65];
  const int bx = blockIdx.x, by = blockIdx.y;
  const int tid = threadIdx.x;
  const int r = tid >> 4;
  const int c4 = tid & 15;
#pragma unroll
  for (int i = 0; i < 4; ++i) {
    int row = r + i * 16;
    float4 v = *reinterpret_cast<const float4*>(
        &W[(size_t)(by * 64 + row) * N + bx * 64 + c4 * 4]);
    t[row][c4 * 4 + 0] = v.x; t[row][c4 * 4 + 1] = v.y;
    t[row][c4 * 4 + 2] = v.z; t[row][c4 * 4 + 3] = v.w;
  }
  __syncthreads();
#pragma unroll
  for (int i = 0; i < 4; ++i) {
    int on = r + i * 16;
    short4 pk;
    pk.x = f2b(t[c4 * 4 + 0][on]);
    pk.y = f2b(t[c4 * 4 + 1][on]);
    pk.z = f2b(t[c4 * 4 + 2][on]);
    pk.w = f2b(t[c4 * 4 + 3][on]);
    *reinterpret_cast<short4*>(&Wt[(size_t)(bx * 64 + on) * K + by * 64 + c4 * 4]) = pk;
  }
}

// ---------------- small GEMM (m97 structure) for prefix projections ----------------
// OM: 1 = bf16 out (MxN), 3 = bf16 transposed out (C^T, N x M layout)
template <int OM>
__global__ __launch_bounds__(256) void gemm_bt(const short* __restrict__ A,
                                               const short* __restrict__ Bt,
                                               void* __restrict__ Cv,
                                               int M, int N, int K) {
  __shared__ short As[128 * 32];
  __shared__ short Bs[128 * 32];
  const int tid = threadIdx.x;
  const int lane = tid & 63;
  const int wbase = tid & 192;
  const int wr = ((tid >> 7) & 1) * 64;
  const int wc = ((tid >> 6) & 1) * 64;
  const int lr = lane & 15;
  const int lk = (lane >> 4) * 8;
  int lin = blockIdx.y * gridDim.x + blockIdx.x;
  int nwg = gridDim.x * gridDim.y;
  int cpx = nwg >> 3;
  int swz = (lin & 7) * cpx + (lin >> 3);
  const int bm = swz / gridDim.x, bn = swz % gridDim.x;
  f32x4 acc[4][4] = {};
  const short* Ab = A + (size_t)bm * 128 * K;
  const short* Bb = Bt + (size_t)bn * 128 * K;
  for (int kt = 0; kt < K; kt += 32) {
    __syncthreads();
#pragma unroll
    for (int i = 0; i < 2; ++i) {
      int f = i * 256 + tid;
      int row = f >> 2, col = (f & 3) * 8;
      gload16(Ab + (size_t)row * K + kt + col, &As[(i * 256 + wbase) * 8]);
      gload16(Bb + (size_t)row * K + kt + col, &Bs[(i * 256 + wbase) * 8]);
    }
    __syncthreads();
    bf16x8 af[4], bfr[4];
#pragma unroll
    for (int m = 0; m < 4; ++m)
      af[m] = *reinterpret_cast<const bf16x8*>(&As[(wr + m * 16 + lr) * 32 + lk]);
#pragma unroll
    for (int n = 0; n < 4; ++n)
      bfr[n] = *reinterpret_cast<const bf16x8*>(&Bs[(wc + n * 16 + lr) * 32 + lk]);
#pragma unroll
    for (int m = 0; m < 4; ++m)
#pragma unroll
      for (int n = 0; n < 4; ++n)
        acc[m][n] = __builtin_amdgcn_mfma_f32_16x16x32_bf16(af[m], bfr[n], acc[m][n], 0, 0, 0);
  }
  const int row0 = bm * 128 + wr + (lane >> 4) * 4;
  const int col0 = bn * 128 + wc + lr;
  if constexpr (OM == 3) {
    short* C = (short*)Cv;
#pragma unroll
    for (int m = 0; m < 4; ++m)
#pragma unroll
      for (int n = 0; n < 4; ++n) {
        short4 pk;
        pk.x = f2b(acc[m][n][0]); pk.y = f2b(acc[m][n][1]);
        pk.z = f2b(acc[m][n][2]); pk.w = f2b(acc[m][n][3]);
        size_t idx = (size_t)(col0 + n * 16) * M + row0 + m * 16;
        *reinterpret_cast<short4*>(&C[idx]) = pk;
      }
  } else {
#pragma unroll
    for (int m = 0; m < 4; ++m)
#pragma unroll
      for (int n = 0; n < 4; ++n)
#pragma unroll
        for (int j = 0; j < 4; ++j) {
          size_t idx = (size_t)(row0 + m * 16 + j) * N + col0 + n * 16;
          ((short*)Cv)[idx] = f2b(acc[m][n][j]);
        }
  }
}

// ---------------- 256x256 8-wave GEMM, kh-major 4-phase, B-frag register reuse ----------------
// (v14 verified: 139 us, MfmaUtil 42%, 0 conflicts)
// ROPE: 0 = none, 1 = rope + 1/sqrt(HD) scale (q), 2 = rope only (k).
// Rope in epilogue: pair (2i,2i+1) = adjacent lanes; partner via shfl_xor(v,1).
#define MFMA16(mh)                                                              \
  _Pragma("unroll") for (int mm = 0; mm < 4; ++mm)                              \
    _Pragma("unroll") for (int nn = 0; nn < 4; ++nn)                            \
      acc[(mh)*4 + mm][nn] = __builtin_amdgcn_mfma_f32_16x16x32_bf16(           \
          af[mm], bf[nn], acc[(mh)*4 + mm][nn], 0, 0, 0);

#define PH_SYNC_PRE                                                             \
  __builtin_amdgcn_s_barrier();                                                 \
  asm volatile("s_waitcnt lgkmcnt(0)" ::: "memory");                            \
  __builtin_amdgcn_sched_barrier(0);                                            \
  __builtin_amdgcn_s_setprio(1);

#define PH_SYNC_POST                                                            \
  __builtin_amdgcn_s_setprio(0);                                                \
  __builtin_amdgcn_s_barrier();

template <int OM, int ROPE>
__global__ __launch_bounds__(512, 2) void gemm256(const short* __restrict__ A,
                                                  const short* __restrict__ Bt,
                                                  void* __restrict__ Cv,
                                                  const float* __restrict__ fc,
                                                  const float* __restrict__ fs,
                                                  int M, int N, int K) {
  __shared__ short As[2][256 * 64];
  __shared__ short Bs[2][256 * 64];
  const int tid = threadIdx.x;
  const int w = tid >> 6;
  const int lane = tid & 63;
  const int lr = lane & 15, lg = lane >> 4;
  const int wr = (w >> 2) * 128;
  const int wc = (w & 3) * 64;
  int lin = blockIdx.y * gridDim.x + blockIdx.x;
  int nwg = gridDim.x * gridDim.y;
  int cpx = nwg >> 3;
  int swz = (lin & 7) * cpx + (lin >> 3);
  const int bm = swz / gridDim.x, bn = swz % gridDim.x;

  const short* Ab = A + (size_t)bm * 256 * K;
  const short* Bb = Bt + (size_t)bn * 256 * K;
  const int NT = K >> 6;

  f32x4 acc[8][4] = {};

  auto stA = [&](int slot_, int r0, int kt) {
    int row = r0 + (lane >> 3);
    int gsrc = (lane & 7) ^ ((lane >> 3) & 7);
    gload16(Ab + (size_t)row * K + kt + gsrc * 8, &As[slot_][r0 * 64]);
  };
  auto stB = [&](int slot_, int r0, int kt) {
    int row = r0 + (lane >> 3);
    int gsrc = (lane & 7) ^ ((lane >> 3) & 7);
    gload16(Bb + (size_t)row * K + kt + gsrc * 8, &Bs[slot_][r0 * 64]);
  };

  const int q2 = w * 2, q4 = w * 4;
  const int rt0 = (q2 < 8 ? 0 : 64) + q2 * 8;
  const int rt1 = (q2 + 1 < 8 ? 0 : 64) + (q2 + 1) * 8;

  {
#pragma unroll
    for (int i = 0; i < 4; ++i) stB(0, (q4 + i) * 8, 0);
    stA(0, rt0, 0); stA(0, 64 + rt0, 0);
    stA(0, rt1, 0); stA(0, 64 + rt1, 0);
#pragma unroll
    for (int i = 0; i < 4; ++i) stB(1, (q4 + i) * 8, 64);
    stA(1, rt0, 64); stA(1, 64 + rt0, 64);
    stA(1, rt1, 64); stA(1, 64 + rt1, 64);
  }
  asm volatile("s_waitcnt vmcnt(8)" ::: "memory");
  __builtin_amdgcn_s_barrier();

  for (int t = 0; t < NT; ++t) {
    const int slot = t & 1;
    const int ns = slot ^ 1;
    const int kt1 = (t + 1) << 6, kt2 = (t + 2) << 6;
    const bool s6 = (t >= 1) && (t + 1 < NT);
    const bool s2 = (t + 2 < NT);
    bf16x8 bf[4], af[4];

    // P1: kh=0, mh=0 — read B(kh0) + A-top(kh0); stage B01(t+1) + A-bottom(t+1)
    {
      const int pg = (lg ^ (lr & 7)) * 8;
#pragma unroll
      for (int nn = 0; nn < 4; ++nn)
        bf[nn] = *(const bf16x8*)&Bs[slot][(wc + nn * 16 + lr) * 64 + pg];
#pragma unroll
      for (int mm = 0; mm < 4; ++mm)
        af[mm] = *(const bf16x8*)&As[slot][(wr + mm * 16 + lr) * 64 + pg];
      if (s6) { stB(ns, (q4 + 0) * 8, kt1); stB(ns, (q4 + 1) * 8, kt1);
                stA(ns, 64 + rt0, kt1);     stA(ns, 64 + rt1, kt1); }
      PH_SYNC_PRE
      MFMA16(0)
      PH_SYNC_POST
    }
    // P2: kh=0, mh=1 — read A-bottom(kh0), reuse bf; stage B23(t+1)
    {
      const int pg = (lg ^ (lr & 7)) * 8;
#pragma unroll
      for (int mm = 0; mm < 4; ++mm)
        af[mm] = *(const bf16x8*)&As[slot][(wr + 64 + mm * 16 + lr) * 64 + pg];
      if (s6) { stB(ns, (q4 + 2) * 8, kt1); stB(ns, (q4 + 3) * 8, kt1); }
      PH_SYNC_PRE
      MFMA16(1)
      PH_SYNC_POST
    }
    // P3: kh=1, mh=0 — read B(kh1) + A-top(kh1)
    {
      const int pg = ((4 + lg) ^ (lr & 7)) * 8;
#pragma unroll
      for (int nn = 0; nn < 4; ++nn)
        bf[nn] = *(const bf16x8*)&Bs[slot][(wc + nn * 16 + lr) * 64 + pg];
#pragma unroll
      for (int mm = 0; mm < 4; ++mm)
        af[mm] = *(const bf16x8*)&As[slot][(wr + mm * 16 + lr) * 64 + pg];
      PH_SYNC_PRE
      MFMA16(0)
      PH_SYNC_POST
    }
    // P4: kh=1, mh=1 — read A-bottom(kh1), reuse bf; stage A-top(t+2); TAIL vmcnt
    {
      const int pg = ((4 + lg) ^ (lr & 7)) * 8;
#pragma unroll
      for (int mm = 0; mm < 4; ++mm)
        af[mm] = *(const bf16x8*)&As[slot][(wr + 64 + mm * 16 + lr) * 64 + pg];
      if (s2) { stA(slot, rt0, kt2); stA(slot, rt1, kt2); }
      PH_SYNC_PRE
      MFMA16(1)
      __builtin_amdgcn_s_setprio(0);
      if (s2) asm volatile("s_waitcnt vmcnt(2)" ::: "memory");
      else    asm volatile("s_waitcnt vmcnt(0)" ::: "memory");
      __builtin_amdgcn_s_barrier();
    }
  }

  const int row0 = bm * 256 + wr + lg * 4;
  const int col0 = bn * 256 + wc + lr;
  if constexpr (OM == 2) {
    short* C = (short*)Cv;
#pragma unroll
    for (int mf = 0; mf < 8; ++mf)
#pragma unroll
      for (int n = 0; n < 4; ++n) {
        int r0 = row0 + mf * 16;
        int bb = r0 >> 11, s0 = r0 & 2047;
        short4 pk;
        pk.x = f2b(acc[mf][n][0]); pk.y = f2b(acc[mf][n][1]);
        pk.z = f2b(acc[mf][n][2]); pk.w = f2b(acc[mf][n][3]);
        size_t idx = ((size_t)(bb * 4096 + col0 + n * 16)) * 2048 + s0;
        *reinterpret_cast<short4*>(&C[idx]) = pk;
      }
  } else if constexpr (OM == 1) {
    short* C = (short*)Cv;
    const float qs = (ROPE == 1) ? 0.08838834764831845f : 1.0f;
#pragma unroll
    for (int mf = 0; mf < 8; ++mf)
#pragma unroll
      for (int n = 0; n < 4; ++n) {
        int col = col0 + n * 16;
#pragma unroll
        for (int j = 0; j < 4; ++j) {
          int row = row0 + mf * 16 + j;
          float v = acc[mf][n][j];
          if constexpr (ROPE > 0) {
            int s = row & 2047;
            int i0 = (col & 127) >> 1;
            float c = fc[s * 64 + i0];
            float sn = fs[s * 64 + i0];
            float p = __shfl_xor(v, 1);
            v = (col & 1) ? (p * sn + v * c) : (v * c - p * sn);
            v *= qs;
          }
          C[(size_t)row * N + col] = f2b(v);
        }
      }
  } else {
#pragma unroll
    for (int mf = 0; mf < 8; ++mf)
#pragma unroll
      for (int n = 0; n < 4; ++n)
#pragma unroll
        for (int j = 0; j < 4; ++j) {
          size_t idx = (size_t)(row0 + mf * 16 + j) * N + col0 + n * 16;
          ((float*)Cv)[idx] = acc[mf][n][j];
        }
  }
}

// ---------------- fused flash attention + gated prefix, 256 q-rows/block ----------------
// 16 waves x 16 rows, LPT grid. K AND V double-buffered via global_load_lds:
// ONE barrier per tile. Q pre-scaled (rope fused in gemm). Diag-only masking. T13.
// LDS: Ks 32K + Vs 32K + Ps 32K = 96 KB.
__global__ __launch_bounds__(1024, 4) void attn_kernel(
    const short* __restrict__ qb, const short* __restrict__ kb, const short* __restrict__ vt,
    const short* __restrict__ pkb, const short* __restrict__ pvt,
    const float* __restrict__ gate, short* __restrict__ ab) {
  __shared__ short Ks[2][64 * 128];
  __shared__ short Vs[2][128 * 64];
  __shared__ short Ps[16][16 * 64];
  const int tid = threadIdx.x;
  const int wave = tid >> 6, lane = tid & 63;
  const int lr = lane & 15, lg = lane >> 4;
  const int lin = blockIdx.x;
  const int qt = 7 - (lin >> 6);     // heavy blocks dispatch first (LPT)
  const int bh = lin & 63;
  const int b = bh >> 5, h = bh & 31;

  bf16x8 aq[4];
  {
    const short* qrow = qb + ((size_t)(b * S_ + qt * 256 + wave * 16 + lr) * H_ + h) * HD_;
#pragma unroll
    for (int kk = 0; kk < 4; ++kk)
      aq[kk] = *reinterpret_cast<const bf16x8*>(qrow + kk * 32 + lg * 8);
  }

  float m = -1e30f, l = 0.f, l2 = 0.f;
  f32x4 o[8] = {}, o2[8] = {};

  const short* kb_bh = kb + ((size_t)b * S_ * H_ + h) * HD_;
  const short* vt_bh = vt + ((size_t)(b * H_ + h)) * HD_ * S_;

  auto stageK = [&](int t, int buf) {
    int row = tid >> 4;
    int col = ((tid & 15) ^ (row & 7)) * 8;
    gload16(kb_bh + (size_t)(t * 64 + row) * (H_ * HD_) + col,
            &Ks[buf][(tid & 960) * 8]);
  };
  auto stagePK = [&](int buf) {
    int row = tid >> 4;
    int col = ((tid & 15) ^ (row & 7)) * 8;
    gload16(pkb + (size_t)row * 4096 + h * HD_ + col, &Ks[buf][(tid & 960) * 8]);
  };
  auto stageV = [&](int t, int buf) {
    int row = tid >> 3;
    int col = ((tid & 7) ^ (row & 7)) * 8;
    gload16(vt_bh + (size_t)row * S_ + t * 64 + col, &Vs[buf][(tid & 1016) * 8]);
  };
  auto stagePV = [&](int buf) {
    int row = tid >> 3;
    int col = ((tid & 7) ^ (row & 7)) * 8;
    gload16(pvt + ((size_t)h * HD_ + row) * 128 + col, &Vs[buf][(tid & 1016) * 8]);
  };

  auto qkt = [&](int buf, f32x4 sc[4]) {
    __builtin_amdgcn_s_setprio(1);
#pragma unroll
    for (int cb = 0; cb < 4; ++cb) {
      int tok = cb * 16 + lr;
#pragma unroll
      for (int kk = 0; kk < 4; ++kk) {
        int addr = tok * 128 + (((kk * 4 + lg) ^ (tok & 7)) * 8);
        bf16x8 bk = *reinterpret_cast<const bf16x8*>(&Ks[buf][addr]);
        sc[cb] = __builtin_amdgcn_mfma_f32_16x16x32_bf16(bk, aq[kk], sc[cb], 0, 0, 0);
      }
    }
    __builtin_amdgcn_s_setprio(0);
  };
  auto pv = [&](int buf, f32x4* acc_) {
#pragma unroll
    for (int kk = 0; kk < 2; ++kk) {
      bf16x8 ap = *reinterpret_cast<const bf16x8*>(
          &Ps[wave][lr * 64 + (((kk * 4 + lg) ^ (lr & 7)) * 8)]);
      __builtin_amdgcn_s_setprio(1);
#pragma unroll
      for (int nb = 0; nb < 8; ++nb) {
        int d = nb * 16 + lr;
        bf16x8 bv = *reinterpret_cast<const bf16x8*>(
            &Vs[buf][d * 64 + (((kk * 4 + lg) ^ (lr & 7)) * 8)]);
        acc_[nb] = __builtin_amdgcn_mfma_f32_16x16x32_bf16(ap, bv, acc_[nb], 0, 0, 0);
      }
      __builtin_amdgcn_s_setprio(0);
    }
  };

  auto process = [&](int t, bool diag) {
    const int buf = t & 1;
    f32x4 sc[4] = {};
    qkt(buf, sc);
    if (diag) {
      const int rowg = qt * 256 + wave * 16 + lr;
#pragma unroll
      for (int cb = 0; cb < 4; ++cb)
#pragma unroll
        for (int j = 0; j < 4; ++j) {
          int colg = t * 64 + cb * 16 + lg * 4 + j;
          if (colg > rowg) sc[cb][j] = -1e30f;
        }
    }
    float mx = sc[0][0];
#pragma unroll
    for (int cb = 0; cb < 4; ++cb)
#pragma unroll
      for (int j = 0; j < 4; ++j) mx = fmaxf(mx, sc[cb][j]);
    mx = fmaxf(mx, __shfl_xor(mx, 16));
    mx = fmaxf(mx, __shfl_xor(mx, 32));
    if (!__all(mx <= m + 8.f)) {
      float mn = fmaxf(m, mx);
      float alpha = __expf(m - mn);
      m = mn;
      l *= alpha;
      f32x4 av;
#pragma unroll
      for (int j = 0; j < 4; ++j) av[j] = __shfl(alpha, lg * 4 + j);
#pragma unroll
      for (int nb = 0; nb < 8; ++nb)
#pragma unroll
        for (int j = 0; j < 4; ++j) o[nb][j] *= av[j];
    }
    float rs = 0.f;
#pragma unroll
    for (int cb = 0; cb < 4; ++cb) {
      short4 pk;
      float p0 = __expf(sc[cb][0] - m);
      float p1 = __expf(sc[cb][1] - m);
      float p2 = __expf(sc[cb][2] - m);
      float p3 = __expf(sc[cb][3] - m);
      rs += (p0 + p1) + (p2 + p3);
      pk.x = f2b(p0); pk.y = f2b(p1); pk.z = f2b(p2); pk.w = f2b(p3);
      int gran = (cb * 2 + (lg >> 1)) ^ (lr & 7);
      *reinterpret_cast<short4*>(&Ps[wave][lr * 64 + gran * 8 + (lg & 1) * 4]) = pk;
    }
    rs += __shfl_xor(rs, 16);
    rs += __shfl_xor(rs, 32);
    l += rs;
    pv(buf, o);
  };

  auto processPrefix = [&]() {
    f32x4 sc[4] = {};
    qkt(0, sc);
#pragma unroll
    for (int cb = 0; cb < 4; ++cb)
#pragma unroll
      for (int j = 0; j < 4; ++j) {
        int coll = cb * 16 + lg * 4 + j;
        if (coll >= P_) sc[cb][j] = -1e30f;
      }
    float mx = sc[0][0];
#pragma unroll
    for (int cb = 0; cb < 4; ++cb)
#pragma unroll
      for (int j = 0; j < 4; ++j) mx = fmaxf(mx, sc[cb][j]);
    mx = fmaxf(mx, __shfl_xor(mx, 16));
    mx = fmaxf(mx, __shfl_xor(mx, 32));
    float rs = 0.f;
#pragma unroll
    for (int cb = 0; cb < 4; ++cb) {
      short4 pk;
      float p0 = __expf(sc[cb][0] - mx);
      float p1 = __expf(sc[cb][1] - mx);
      float p2 = __expf(sc[cb][2] - mx);
      float p3 = __expf(sc[cb][3] - mx);
      rs += (p0 + p1) + (p2 + p3);
      pk.x = f2b(p0); pk.y = f2b(p1); pk.z = f2b(p2); pk.w = f2b(p3);
      int gran = (cb * 2 + (lg >> 1)) ^ (lr & 7);
      *reinterpret_cast<short4*>(&Ps[wave][lr * 64 + gran * 8 + (lg & 1) * 4]) = pk;
    }
    rs += __shfl_xor(rs, 16);
    rs += __shfl_xor(rs, 32);
    l2 = rs;
    pv(0, o2);
  };

  const int nt = 4 * (qt + 1);

  stagePK(0);
  stagePV(0);
  __syncthreads();
  processPrefix();
  __syncthreads();

  stageK(0, 0);
  stageV(0, 0);
  __syncthreads();
  for (int t = 0; t < nt; ++t) {
    if (t + 1 < nt) {
      stageK(t + 1, (t + 1) & 1);
      stageV(t + 1, (t + 1) & 1);
    }
    process(t, t >= 4 * qt);
    __syncthreads();
  }

  {
    float g = tanhf(gate[h]);
    f32x4 lv, lv2;
#pragma unroll
    for (int j = 0; j < 4; ++j) {
      lv[j] = __shfl(l, lg * 4 + j);
      lv2[j] = __shfl(l2, lg * 4 + j);
    }
#pragma unroll
    for (int j = 0; j < 4; ++j) {
      int q = qt * 256 + wave * 16 + lg * 4 + j;
      float inv = 1.f / lv[j];
      float inv2 = g / lv2[j];
      size_t base = ((size_t)(b * S_ + q) * H_ + h) * HD_;
#pragma unroll
      for (int nb = 0; nb < 8; ++nb)
        ab[base + nb * 16 + lr] = f2b(o[nb][j] * inv + o2[nb][j] * inv2);
    }
  }
}

// ---------------- launcher ----------------
extern "C" void kernel_launch(void* const* d_in, const int* in_sizes, int n_in,
                              void* d_out, int out_size, void* d_ws, size_t ws_size,
                              hipStream_t stream) {
  const float* x = (const float*)d_in[0];
  const float* fc = (const float*)d_in[1];
  const float* fs = (const float*)d_in[2];
  const float* prefix = (const float*)d_in[3];
  const float* gate = (const float*)d_in[4];
  const float* wq = (const float*)d_in[5];
  const float* wk = (const float*)d_in[6];
  const float* wv = (const float*)d_in[7];
  const float* wo = (const float*)d_in[8];
  float* out = (float*)d_out;

  char* ws = (char*)d_ws;
  const size_t SZ = (size_t)4096 * 4096 * 2;
  short* xb = (short*)(ws);
  short* wT = (short*)(ws + SZ);
  short* qbuf = (short*)(ws + 2 * SZ);
  short* kbuf = (short*)(ws + 3 * SZ);
  short* vT = (short*)(ws + 4 * SZ);
  short* pb = (short*)(ws + 5 * SZ);
  short* pkb = (short*)(ws + 5 * SZ + (1 << 20));
  short* pvt = (short*)(ws + 5 * SZ + (2 << 20));
  short* abuf = xb;  // alias: x_bf16 dead after V projection

  dim3 tcg(64, 64), tcb(256);
  dim3 gg(16, 16), gp(32, 1);

  convert_f32_bf16<<<16384, 256, 0, stream>>>(x, xb);
  pad_prefix<<<2048, 256, 0, stream>>>(prefix, pb);

  transpose_convert<<<tcg, tcb, 0, stream>>>(wq, wT, 4096, 4096);
  gemm256<1, 1><<<gg, 512, 0, stream>>>(xb, wT, qbuf, fc, fs, 4096, 4096, 4096);

  transpose_convert<<<tcg, tcb, 0, stream>>>(wk, wT, 4096, 4096);
  gemm256<1, 2><<<gg, 512, 0, stream>>>(xb, wT, kbuf, fc, fs, 4096, 4096, 4096);
  gemm_bt<1><<<gp, 256, 0, stream>>>(pb, wT, pkb, 128, 4096, 4096);

  transpose_convert<<<tcg, tcb, 0, stream>>>(wv, wT, 4096, 4096);
  gemm256<2, 0><<<gg, 512, 0, stream>>>(xb, wT, vT, nullptr, nullptr, 4096, 4096, 4096);
  gemm_bt<3><<<gp, 256, 0, stream>>>(pb, wT, pvt, 128, 4096, 4096);

  attn_kernel<<<512, 1024, 0, stream>>>(qbuf, kbuf, vT, pkb, pvt, gate, abuf);

  transpose_convert<<<tcg, tcb, 0, stream>>>(wo, wT, 4096, 4096);
  gemm256<0, 0><<<gg, 512, 0, stream>>>(abuf, wT, out, nullptr, nullptr, 4096, 4096, 4096);
}